// Round 1
// 702.665 us; speedup vs baseline: 1.3661x; 1.3661x over previous
//
#include <hip/hip_runtime.h>
#include <math.h>

#define B_   128
#define L_   32
#define T_   31
#define V_   10000
#define IC_  2048
#define WD_  512
#define H_   512
#define D_   2560
#define G3_  1536   // 3*H
#define NPAD_ 10112 // V padded to 79*128
#define NTILE_ (79 * 31)          // consumer tiles (t, nb)
#define NPROD_ 64                 // producer blocks
#define NCONS_ 448                // persistent consumer blocks (64+448=512 = 2/CU)

typedef short short8 __attribute__((ext_vector_type(8)));
typedef float f32x4  __attribute__((ext_vector_type(4)));
typedef unsigned short ushort_t;

__device__ __forceinline__ unsigned short f2bf(float f) {
    unsigned int u = __builtin_bit_cast(unsigned int, f);
    unsigned int r = (u + 0x7FFFu + ((u >> 16) & 1u)) >> 16;
    return (unsigned short)r;
}
__device__ __forceinline__ float bf2f(unsigned short h) {
    unsigned int u = ((unsigned int)h) << 16;
    return __builtin_bit_cast(float, u);
}
__device__ __forceinline__ f32x4 mfma16(short8 a, short8 b, f32x4 c) {
    return __builtin_amdgcn_mfma_f32_16x16x32_bf16(a, b, c, 0, 0, 0);
}

// ---- workspace layout (byte offsets) ----
#define WS_ORDER  0          // int[128]
#define WS_LEN    512        // int[128]
#define WS_TOK    1024       // int[3968] -> ends 16896
#define WS_BAR    16896      // int barrier counter (zeroed by k_prep; producers only)
#define WS_GIIMG  16960      // float[128*1536]          -> ends 803392
#define WS_WHH    803392     // bf16 [32][48][512] perm  -> ends 2376256
#define WS_GIFULL 2376256    // bf16 [3968*1536]         -> ends 14565952
#define WS_OUTS   14565952   // bf16 [32*128*512]        -> ends 18760256
#define WS_FCW    18760256   // bf16 [10112*512]         -> ends 29114944
// per-step ready flags live inside the zero-padded fcw rows [10108,10112):
//   - zeroed every iteration by k_cvt_fcw (rows >= V_ write 0)
//   - read as B-operand only for output cols n >= V_, which are masked
//   31 flags, 128 B apart (one per L3 line-ish), 3968 B <= 4096 B region.

// ---------------------------------------------------------------------------
__global__ void k_prep(const int* __restrict__ captions,
                       const int* __restrict__ cap_lens,
                       int* __restrict__ order,
                       int* __restrict__ len_i,
                       int* __restrict__ tok,
                       int* __restrict__ bar,
                       float* __restrict__ out_tail) {
    __shared__ int s_len[B_];
    __shared__ int s_ord[B_];
    const int tid = threadIdx.x;
    if (tid == 0) *bar = 0;
    if (tid < B_) s_len[tid] = cap_lens[tid];
    __syncthreads();
    if (tid < B_) {
        const int myl = s_len[tid];
        int rank = 0;
        for (int k = 0; k < B_; ++k) {
            const int lk = s_len[k];
            if (lk > myl || (lk == myl && k < tid)) rank++;
        }
        s_ord[rank] = tid;
    }
    __syncthreads();
    if (tid < B_) {
        const int o = s_ord[tid];
        order[tid] = o;
        const int ln = s_len[o] - 1;
        len_i[tid] = ln;
        out_tail[B_ * L_ + tid]      = (float)ln;
        out_tail[B_ * L_ + B_ + tid] = (float)o;
    }
    __syncthreads();
    for (int i = tid; i < B_ * L_; i += blockDim.x) {
        const int b = i / L_, l = i % L_;
        const int c = captions[s_ord[b] * L_ + l];
        out_tail[i] = (float)c;
        if (l < T_) tok[l * B_ + b] = c;
    }
}

// fc_w (10000x512 f32) -> bf16 padded to 10112 rows (zero tail; also zeroes flags)
__global__ void k_cvt_fcw(const float* __restrict__ src, ushort_t* __restrict__ dst) {
    const int idx = blockIdx.x * 256 + threadIdx.x;
    const int row = idx >> 6;
    const int ch  = idx & 63;
    union { unsigned short u[8]; uint4 v; } r;
    if (row < V_) {
        const float* p = src + (size_t)row * 512 + ch * 8;
        const float4 x = *(const float4*)p;
        const float4 y = *(const float4*)(p + 4);
        r.u[0]=f2bf(x.x); r.u[1]=f2bf(x.y); r.u[2]=f2bf(x.z); r.u[3]=f2bf(x.w);
        r.u[4]=f2bf(y.x); r.u[5]=f2bf(y.y); r.u[6]=f2bf(y.z); r.u[7]=f2bf(y.w);
    } else {
        r.v = make_uint4(0, 0, 0, 0);
    }
    *(uint4*)&dst[(size_t)row * 512 + ch * 8] = r.v;
}

// W_hh (1536x512 f32) -> bf16, permuted into 32 slices of 48x512:
// slice g, local row j (= gate*16 + c) <- source row gate*512 + g*16 + c
__global__ void k_cvt_whh(const float* __restrict__ whh, ushort_t* __restrict__ dst) {
    const int idx = blockIdx.x * 256 + threadIdx.x;
    const size_t o = (size_t)idx * 8;
    const int g = (int)(o / (48 * 512));
    const int rem = (int)(o % (48 * 512));
    const int j = rem >> 9;
    const int k = rem & 511;
    const int srow = (j >> 4) * 512 + g * 16 + (j & 15);
    const float* p = whh + (size_t)srow * 512 + k;
    const float4 x = *(const float4*)p;
    const float4 y = *(const float4*)(p + 4);
    union { unsigned short u[8]; uint4 v; } r;
    r.u[0]=f2bf(x.x); r.u[1]=f2bf(x.y); r.u[2]=f2bf(x.z); r.u[3]=f2bf(x.w);
    r.u[4]=f2bf(y.x); r.u[5]=f2bf(y.y); r.u[6]=f2bf(y.z); r.u[7]=f2bf(y.w);
    *(uint4*)&dst[o] = r.v;
}

// ---------------------------------------------------------------------------
template<bool F32>
__device__ __forceinline__ uint4 load_cvt(const void* src, size_t off) {
    if constexpr (!F32) {
        return *(const uint4*)((const unsigned short*)src + off);
    } else {
        const float* p = (const float*)src + off;
        const float4 x = *(const float4*)p;
        const float4 y = *(const float4*)(p + 4);
        union { unsigned short u[8]; uint4 v; } r;
        r.u[0]=f2bf(x.x); r.u[1]=f2bf(x.y); r.u[2]=f2bf(x.z); r.u[3]=f2bf(x.w);
        r.u[4]=f2bf(y.x); r.u[5]=f2bf(y.y); r.u[6]=f2bf(y.z); r.u[7]=f2bf(y.w);
        return r.v;
    }
}

// epilogues for the prefix GEMMs
struct EpiBiasF32 {               // gi_img
    float* C; int ldc; const float* bias;
    __device__ void operator()(int m, int n, float v) const {
        C[(size_t)m * ldc + n] = v + bias[n];
    }
};
struct EpiBiasBF16 {              // h0 -> outs rows [0,128)
    ushort_t* C; int ldc; const float* bias;
    __device__ void operator()(int m, int n, float v) const {
        C[(size_t)m * ldc + n] = f2bf(v + bias[n]);
    }
};
struct EpiAdd2D {                 // gi_full = giw + gi_img[b] (+ b_hh for r,z)
    ushort_t* C; int ldc; const float* add; int addld; const float* bhh;
    __device__ void operator()(int m, int n, float v) const {
        const float extra = (n < 1024) ? bhh[n] : 0.f;
        C[(size_t)m * ldc + n] = f2bf(v + add[(size_t)(m & 127) * addld + n] + extra);
    }
};

// ---------------------------------------------------------------------------
// NT GEMM, 128x128 tile, BK=32, 256 thr / 4 waves, bf16 MFMA 16x16x32.
// ---------------------------------------------------------------------------
template<bool AF32, bool BF32, class Epi>
__global__ __launch_bounds__(256) void gemm128(
    const void* __restrict__ A, int lda, const int* __restrict__ gidx,
    const void* __restrict__ Bm, int ldb, int K, Epi epi)
{
    __shared__ ushort_t As[128 * 32];
    __shared__ ushort_t Bs[128 * 32];
    const int tid = threadIdx.x;
    const int m0 = blockIdx.y * 128, n0 = blockIdx.x * 128;
    const int w = tid >> 6, lane = tid & 63, quad = lane >> 4, lr = lane & 15;
    const int srow = tid >> 2, ch = tid & 3;
    const int wm = (w & 1) * 64, wn = (w >> 1) * 64;

    const int ar0 = gidx ? gidx[m0 + srow]      : (m0 + srow);
    const int ar1 = gidx ? gidx[m0 + srow + 64] : (m0 + srow + 64);
    const int br0 = n0 + srow, br1 = n0 + srow + 64;

    f32x4 acc[4][4];
    const f32x4 z4 = {0.f, 0.f, 0.f, 0.f};
#pragma unroll
    for (int i = 0; i < 4; ++i)
#pragma unroll
        for (int j = 0; j < 4; ++j) acc[i][j] = z4;

    for (int k0 = 0; k0 < K; k0 += 32) {
        const uint4 a0 = load_cvt<AF32>(A, (size_t)ar0 * lda + k0 + ch * 8);
        const uint4 a1 = load_cvt<AF32>(A, (size_t)ar1 * lda + k0 + ch * 8);
        const uint4 b0 = load_cvt<BF32>(Bm, (size_t)br0 * ldb + k0 + ch * 8);
        const uint4 b1 = load_cvt<BF32>(Bm, (size_t)br1 * ldb + k0 + ch * 8);
        __syncthreads();
        *(uint4*)&As[(srow)      * 32 + ch * 8] = a0;
        *(uint4*)&As[(srow + 64) * 32 + ch * 8] = a1;
        *(uint4*)&Bs[(srow)      * 32 + ch * 8] = b0;
        *(uint4*)&Bs[(srow + 64) * 32 + ch * 8] = b1;
        __syncthreads();
        short8 af[4], bfr[4];
#pragma unroll
        for (int i = 0; i < 4; ++i) af[i]  = *(const short8*)&As[(wm + i * 16 + lr) * 32 + quad * 8];
#pragma unroll
        for (int j = 0; j < 4; ++j) bfr[j] = *(const short8*)&Bs[(wn + j * 16 + lr) * 32 + quad * 8];
#pragma unroll
        for (int i = 0; i < 4; ++i)
#pragma unroll
            for (int j = 0; j < 4; ++j) acc[i][j] = mfma16(af[i], bfr[j], acc[i][j]);
    }

#pragma unroll
    for (int i = 0; i < 4; ++i)
#pragma unroll
        for (int r = 0; r < 4; ++r) {
            const int m = m0 + wm + i * 16 + quad * 4 + r;
#pragma unroll
            for (int j = 0; j < 4; ++j) {
                const int n = n0 + wn + j * 16 + lr;
                epi(m, n, acc[i][j][r]);
            }
        }
}

// ---------------------------------------------------------------------------
// FUSED recurrence + output projection.
//
// Producers [0,64): g = bid&31 (16 gh cols x 3 gates), ih = bid>>5. W slice
//   48x512 LDS-resident. Per step: h A-fragments loaded DIRECTLY to registers
//   (16 x uint4 per lane, plain cached loads -- every outs slot is written
//   (write-through, vmcnt(0)-drained) strictly before first read, so no cache
//   can hold a pre-write copy; cross-iteration stale lines are benign because
//   the computation is bit-deterministic per replay). 48 MFMA, gates in regs,
//   write-through h store, producers-only counter barrier on bar; the LAST
//   arriver publishes a per-step ready flag on its own padded line.
// Consumers [64,512): PERSISTENT. Block c handles tiles tix = c, c+448, ...
//   (tix = t*79 + nb, monotone t per block). Wait on flags[t] (not bar!),
//   then 128x128 K=512 MFMA GEMM h_{t+1} @ fcw^T, masked transposed
//   nontemporal store (out stream must not evict fcw from L3).
// LDS: 48*520 ush = 49,920 B -> 2 blocks/CU; grid 512 = exactly 2/CU.
// ---------------------------------------------------------------------------
#define PBS_STR 520
__global__ __launch_bounds__(256, 2) void k_fused(
    const ushort_t* __restrict__ whh_bf,   // (32,48,512)
    const ushort_t* __restrict__ gi_full,  // (31*128,1536)
    const float* __restrict__ b_hh,        // (1536)
    ushort_t* __restrict__ outs,           // (32,128,512)
    const ushort_t* __restrict__ fcw_bf,   // (10112,512)
    const float* __restrict__ fc_b,        // (10000)
    const int* __restrict__ len_i,         // (128)
    float* __restrict__ out,               // (128,31,10000)
    int* __restrict__ bar,                 // producers-only counter
    int* __restrict__ flags)               // 31 x (128B-strided) ready flags
{
    __shared__ __align__(16) ushort_t sm[48 * PBS_STR];
    const int bid = blockIdx.x;
    const int tid = threadIdx.x;
    const int w = tid >> 6, lane = tid & 63, quad = lane >> 4, lr = lane & 15;

    if (bid < NPROD_) {
        // ---------------- producer ----------------
        __builtin_amdgcn_s_setprio(1);     // latency-critical waves win issue arb
        const int g = bid & 31;
        const int ih = bid >> 5;
        ushort_t* Bs = sm;                 // 48 x 520

        const ushort_t* wsrc = whh_bf + (size_t)g * 48 * 512;
        for (int i = tid; i < 48 * 64; i += 256) {
            const int row = i >> 6, c = i & 63;
            *(uint4*)&Bs[row * PBS_STR + c * 8] = *(const uint4*)&wsrc[row * 512 + c * 8];
        }
        const int cg = g * 16 + lr;        // gh col
        const float bhn = b_hh[1024 + cg];
        __syncthreads();

        for (int step = 0; step < T_; ++step) {
            const ushort_t* hsrc = outs + (size_t)step * (128 * 512) + (size_t)ih * 64 * 512;

            // gi operands (cached; issued early, consumed late)
            ushort_t gi0[4], gi1[4], gi2[4];
            const size_t gbase = (size_t)step * 128 * G3_;
#pragma unroll
            for (int r = 0; r < 4; ++r) {
                const int b = ih * 64 + w * 16 + quad * 4 + r;
                const ushort_t* p = gi_full + gbase + (size_t)b * G3_ + cg;
                gi0[r] = p[0]; gi1[r] = p[512]; gi2[r] = p[1024];
            }
            // own h_t values for the z-blend
            ushort_t hraw[4];
#pragma unroll
            for (int r = 0; r < 4; ++r)
                hraw[r] = hsrc[(size_t)(w * 16 + quad * 4 + r) * 512 + cg];

            // h_t A-fragments: per-lane contiguous 16B chunks straight to regs
            uint4 hv[16];
            const ushort_t* hrow = hsrc + (size_t)(w * 16 + lr) * 512 + quad * 8;
#pragma unroll
            for (int kk = 0; kk < 16; ++kk)
                hv[kk] = *(const uint4*)(hrow + kk * 32);

            f32x4 acc[3];
#pragma unroll
            for (int j = 0; j < 3; ++j) acc[j] = (f32x4){0.f, 0.f, 0.f, 0.f};
#pragma unroll
            for (int kk = 0; kk < 16; ++kk) {
                union { uint4 v; short8 s; } cc; cc.v = hv[kk];
                const short8 af = cc.s;
#pragma unroll
                for (int j = 0; j < 3; ++j) {
                    const short8 bf = *(const short8*)&Bs[(j * 16 + lr) * PBS_STR + kk * 32 + quad * 8];
                    acc[j] = mfma16(af, bf, acc[j]);
                }
            }

            // gates (C-layout: col=lr, row=quad*4+r)
            ushort_t* hdst = outs + (size_t)(step + 1) * (128 * 512);
#pragma unroll
            for (int r = 0; r < 4; ++r) {
                const int b = ih * 64 + w * 16 + quad * 4 + r;
                const float ir  = bf2f(gi0[r]);
                const float iz  = bf2f(gi1[r]);
                const float in_ = bf2f(gi2[r]);
                const float hr = acc[0][r];
                const float hz = acc[1][r];
                const float hn = acc[2][r] + bhn;
                const float rg = 1.f / (1.f + __expf(-(ir + hr)));
                const float zg = 1.f / (1.f + __expf(-(iz + hz)));
                const float nn = tanhf(in_ + rg * hn);
                const float hold = bf2f(hraw[r]);
                const float hnew = (1.f - zg) * nn + zg * hold;
                const unsigned int hb = (unsigned int)f2bf(hnew);
                const unsigned int pv = (unsigned int)__shfl_xor((int)hb, 1);
                if ((lr & 1) == 0) {
                    const unsigned int word = hb | (pv << 16);
                    __hip_atomic_store((unsigned int*)&hdst[(size_t)b * 512 + cg], word,
                                       __ATOMIC_RELAXED, __HIP_MEMORY_SCOPE_AGENT);
                }
            }

            // release: drain write-through stores, then signal
            asm volatile("s_waitcnt vmcnt(0)" ::: "memory");
            __syncthreads();
            if (tid == 0) {
                const int old = __hip_atomic_fetch_add(bar, 1, __ATOMIC_RELAXED, __HIP_MEMORY_SCOPE_AGENT);
                const int target = NPROD_ * (step + 1);
                if (old == target - 1)   // last arriver publishes step-ready flag
                    __hip_atomic_store(&flags[step * 32], 1,
                                       __ATOMIC_RELAXED, __HIP_MEMORY_SCOPE_AGENT);
                if (step < T_ - 1) {
                    while (__hip_atomic_load(bar, __ATOMIC_RELAXED, __HIP_MEMORY_SCOPE_AGENT) < target)
                        __builtin_amdgcn_s_sleep(2);
                }
            }
            __syncthreads();
            asm volatile("" ::: "memory");
        }
    } else {
        // ---------------- persistent consumer (preds tiles) ----------------
        const int cid = bid - NPROD_;
        ushort_t* As = sm;            // 128 x 32
        ushort_t* Bs = sm + 4096;     // 128 x 32
        const int srow = tid >> 2, ch = tid & 3;
        const int wm = (w & 1) * 64, wn = (w >> 1) * 64;

        for (int tix = cid; tix < NTILE_; tix += NCONS_) {
            const int t = tix / 79;
            const int nb = tix - t * 79;
            const int n0 = nb * 128;

            if (tid == 0) {
                while (__hip_atomic_load(&flags[t * 32], __ATOMIC_RELAXED, __HIP_MEMORY_SCOPE_AGENT) == 0)
                    __builtin_amdgcn_s_sleep(32);
            }
            __syncthreads();

            const ushort_t* A = outs + (size_t)(t + 1) * (128 * 512);

            f32x4 acc[4][4];
            const f32x4 z4 = {0.f, 0.f, 0.f, 0.f};
#pragma unroll
            for (int i = 0; i < 4; ++i)
#pragma unroll
                for (int j = 0; j < 4; ++j) acc[i][j] = z4;

            for (int k0 = 0; k0 < 512; k0 += 32) {
                const uint4 a0 = *(const uint4*)&A[(size_t)srow * 512 + k0 + ch * 8];
                const uint4 a1 = *(const uint4*)&A[(size_t)(srow + 64) * 512 + k0 + ch * 8];
                const uint4 b0 = *(const uint4*)&fcw_bf[(size_t)(n0 + srow)      * 512 + k0 + ch * 8];
                const uint4 b1 = *(const uint4*)&fcw_bf[(size_t)(n0 + srow + 64) * 512 + k0 + ch * 8];
                __syncthreads();
                *(uint4*)&As[(srow)      * 32 + ch * 8] = a0;
                *(uint4*)&As[(srow + 64) * 32 + ch * 8] = a1;
                *(uint4*)&Bs[(srow)      * 32 + ch * 8] = b0;
                *(uint4*)&Bs[(srow + 64) * 32 + ch * 8] = b1;
                __syncthreads();
                short8 af[4], bfr[4];
#pragma unroll
                for (int i = 0; i < 4; ++i) af[i]  = *(const short8*)&As[(wm + i * 16 + lr) * 32 + quad * 8];
#pragma unroll
                for (int j = 0; j < 4; ++j) bfr[j] = *(const short8*)&Bs[(wn + j * 16 + lr) * 32 + quad * 8];
#pragma unroll
                for (int i = 0; i < 4; ++i)
#pragma unroll
                    for (int j = 0; j < 4; ++j) acc[i][j] = mfma16(af[i], bfr[j], acc[i][j]);
            }

#pragma unroll
            for (int i = 0; i < 4; ++i)
#pragma unroll
                for (int r = 0; r < 4; ++r) {
                    const int b = wm + i * 16 + quad * 4 + r;
                    const bool act = (t < len_i[b]);
                    const size_t base = (size_t)b * T_ * V_ + (size_t)t * V_;
#pragma unroll
                    for (int j = 0; j < 4; ++j) {
                        const int n = n0 + wn + j * 16 + lr;
                        if (n < V_)
                            __builtin_nontemporal_store(act ? (acc[i][j][r] + fc_b[n]) : 0.f,
                                                        &out[base + n]);
                    }
                }
        }
    }
}

// ---------------------------------------------------------------------------
extern "C" void kernel_launch(void* const* d_in, const int* in_sizes, int n_in,
                              void* d_out, int out_size, void* d_ws, size_t ws_size,
                              hipStream_t stream) {
    const float* image_code = (const float*)d_in[0];
    const int*   captions   = (const int*)d_in[1];
    const int*   cap_lens   = (const int*)d_in[2];
    const float* embed_w    = (const float*)d_in[3];
    const float* W_ih       = (const float*)d_in[4];
    const float* W_hh       = (const float*)d_in[5];
    const float* b_ih       = (const float*)d_in[6];
    const float* b_hh       = (const float*)d_in[7];
    const float* fc_w       = (const float*)d_in[8];
    const float* fc_b       = (const float*)d_in[9];
    const float* init_w     = (const float*)d_in[10];
    const float* init_b     = (const float*)d_in[11];

    float* out = (float*)d_out;
    char* ws = (char*)d_ws;
    int*      order   = (int*)(ws + WS_ORDER);
    int*      len_i   = (int*)(ws + WS_LEN);
    int*      tok     = (int*)(ws + WS_TOK);
    int*      bar     = (int*)(ws + WS_BAR);
    float*    gi_img  = (float*)(ws + WS_GIIMG);
    ushort_t* whh_bf  = (ushort_t*)(ws + WS_WHH);
    ushort_t* gi_full = (ushort_t*)(ws + WS_GIFULL);
    ushort_t* outs_bf = (ushort_t*)(ws + WS_OUTS);
    ushort_t* fcw_bf  = (ushort_t*)(ws + WS_FCW);
    // flags overlay the zero-padded fcw rows [10108,10112) (4096 B, masked)
    int*      flags   = (int*)(fcw_bf + ((size_t)NPAD_ - 4) * 512);

    // 1) sort + token table + barrier reset + int-ish outputs
    hipLaunchKernelGGL(k_prep, dim3(1), dim3(128), 0, stream,
                       captions, cap_lens, order, len_i, tok, bar,
                       out + (size_t)B_ * T_ * V_);

    // 2) weight conversions (k_cvt_fcw also zeroes the flag region each iter)
    hipLaunchKernelGGL(k_cvt_fcw, dim3((NPAD_ * 64) / 256), dim3(256), 0, stream,
                       fc_w, fcw_bf);
    hipLaunchKernelGGL(k_cvt_whh, dim3((G3_ * H_ / 8) / 256), dim3(256), 0, stream,
                       W_hh, whh_bf);

    // 3) gi_img = ic_s @ W_ih[:, :2048]^T + b_ih
    hipLaunchKernelGGL((gemm128<true, true, EpiBiasF32>), dim3(12, 1), dim3(256), 0, stream,
                       image_code, IC_, order, W_ih, D_, IC_,
                       EpiBiasF32{gi_img, G3_, b_ih});

    // 4) h0 = ic_s @ init_w^T + init_b -> outs rows [0,128)
    hipLaunchKernelGGL((gemm128<true, true, EpiBiasBF16>), dim3(4, 1), dim3(256), 0, stream,
                       image_code, IC_, order, init_w, IC_, IC_,
                       EpiBiasBF16{outs_bf, H_, init_b});

    // 5) gi_full = emb @ W_ih[:, 2048:]^T + gi_img[b] + b_hh(r,z)
    hipLaunchKernelGGL((gemm128<true, true, EpiAdd2D>), dim3(12, 31), dim3(256), 0, stream,
                       embed_w, WD_, tok, W_ih + IC_, D_, WD_,
                       EpiAdd2D{gi_full, G3_, gi_img, G3_, b_hh});

    // 6) fused persistent recurrence + streaming output projection
    hipLaunchKernelGGL(k_fused, dim3(NPROD_ + NCONS_), dim3(256), 0, stream,
                       whh_bf, gi_full, b_hh, outs_bf,
                       fcw_bf, fc_b, len_i, out, bar, flags);
}

// Round 2
// 665.302 us; speedup vs baseline: 1.4429x; 1.0562x over previous
//
#include <hip/hip_runtime.h>
#include <math.h>

#define B_   128
#define L_   32
#define T_   31
#define V_   10000
#define IC_  2048
#define WD_  512
#define H_   512
#define D_   2560
#define G3_  1536   // 3*H
#define NPAD_ 10112 // V padded to 79*128
#define NTILE_ (79 * 31)          // consumer tiles (t, nb)
#define NPROD_ 64                 // producer blocks
#define NCONS_ 448                // persistent consumer blocks (64+448=512 = 2/CU)

typedef short short8 __attribute__((ext_vector_type(8)));
typedef float f32x4  __attribute__((ext_vector_type(4)));
typedef unsigned short ushort_t;
typedef unsigned long long ull_t;

__device__ __forceinline__ unsigned short f2bf(float f) {
    unsigned int u = __builtin_bit_cast(unsigned int, f);
    unsigned int r = (u + 0x7FFFu + ((u >> 16) & 1u)) >> 16;
    return (unsigned short)r;
}
__device__ __forceinline__ float bf2f(unsigned short h) {
    unsigned int u = ((unsigned int)h) << 16;
    return __builtin_bit_cast(float, u);
}
__device__ __forceinline__ f32x4 mfma16(short8 a, short8 b, f32x4 c) {
    return __builtin_amdgcn_mfma_f32_16x16x32_bf16(a, b, c, 0, 0, 0);
}

// ---- workspace layout (byte offsets) ----
#define WS_ORDER  0          // int[128]
#define WS_LEN    512        // int[128]
#define WS_TOK    1024       // int[3968] -> ends 16896
#define WS_BAR    16896      // int (legacy, zeroed, unused by k_fused)
#define WS_GIIMG  16960      // float[128*1536]          -> ends 803392
#define WS_WHH    803392     // bf16 [32][48][512] perm  -> ends 2376256
#define WS_GIFULL 2376256    // bf16 [3968*1536]         -> ends 14565952
#define WS_OUTS   14565952   // bf16 [32*128*512]        -> ends 18760256
#define WS_FCW    18760256   // bf16 [10112*512]         -> ends 29114944
// sync flags live inside the zero-padded fcw rows [10108,10112) (4096 B):
//   - zeroed every iteration by k_cvt_fcw (rows >= V_ write 0)
//   - read as B-operand only for output cols n >= V_, which are masked
//   sync[i*8]   : per-producer flag i in [0,64), value = step+1 (32B stride)
//   sync[512+ih]: half-ready flag (packed pair readable as one 8B load)

// ---------------------------------------------------------------------------
__global__ void k_prep(const int* __restrict__ captions,
                       const int* __restrict__ cap_lens,
                       int* __restrict__ order,
                       int* __restrict__ len_i,
                       int* __restrict__ tok,
                       int* __restrict__ bar,
                       float* __restrict__ out_tail) {
    __shared__ int s_len[B_];
    __shared__ int s_ord[B_];
    const int tid = threadIdx.x;
    if (tid == 0) *bar = 0;
    if (tid < B_) s_len[tid] = cap_lens[tid];
    __syncthreads();
    if (tid < B_) {
        const int myl = s_len[tid];
        int rank = 0;
        for (int k = 0; k < B_; ++k) {
            const int lk = s_len[k];
            if (lk > myl || (lk == myl && k < tid)) rank++;
        }
        s_ord[rank] = tid;
    }
    __syncthreads();
    if (tid < B_) {
        const int o = s_ord[tid];
        order[tid] = o;
        const int ln = s_len[o] - 1;
        len_i[tid] = ln;
        out_tail[B_ * L_ + tid]      = (float)ln;
        out_tail[B_ * L_ + B_ + tid] = (float)o;
    }
    __syncthreads();
    for (int i = tid; i < B_ * L_; i += blockDim.x) {
        const int b = i / L_, l = i % L_;
        const int c = captions[s_ord[b] * L_ + l];
        out_tail[i] = (float)c;
        if (l < T_) tok[l * B_ + b] = c;
    }
}

// fc_w (10000x512 f32) -> bf16 padded to 10112 rows (zero tail; also zeroes flags)
__global__ void k_cvt_fcw(const float* __restrict__ src, ushort_t* __restrict__ dst) {
    const int idx = blockIdx.x * 256 + threadIdx.x;
    const int row = idx >> 6;
    const int ch  = idx & 63;
    union { unsigned short u[8]; uint4 v; } r;
    if (row < V_) {
        const float* p = src + (size_t)row * 512 + ch * 8;
        const float4 x = *(const float4*)p;
        const float4 y = *(const float4*)(p + 4);
        r.u[0]=f2bf(x.x); r.u[1]=f2bf(x.y); r.u[2]=f2bf(x.z); r.u[3]=f2bf(x.w);
        r.u[4]=f2bf(y.x); r.u[5]=f2bf(y.y); r.u[6]=f2bf(y.z); r.u[7]=f2bf(y.w);
    } else {
        r.v = make_uint4(0, 0, 0, 0);
    }
    *(uint4*)&dst[(size_t)row * 512 + ch * 8] = r.v;
}

// W_hh (1536x512 f32) -> bf16, permuted into 32 slices of 48x512:
// slice g, local row j (= gate*16 + c) <- source row gate*512 + g*16 + c
__global__ void k_cvt_whh(const float* __restrict__ whh, ushort_t* __restrict__ dst) {
    const int idx = blockIdx.x * 256 + threadIdx.x;
    const size_t o = (size_t)idx * 8;
    const int g = (int)(o / (48 * 512));
    const int rem = (int)(o % (48 * 512));
    const int j = rem >> 9;
    const int k = rem & 511;
    const int srow = (j >> 4) * 512 + g * 16 + (j & 15);
    const float* p = whh + (size_t)srow * 512 + k;
    const float4 x = *(const float4*)p;
    const float4 y = *(const float4*)(p + 4);
    union { unsigned short u[8]; uint4 v; } r;
    r.u[0]=f2bf(x.x); r.u[1]=f2bf(x.y); r.u[2]=f2bf(x.z); r.u[3]=f2bf(x.w);
    r.u[4]=f2bf(y.x); r.u[5]=f2bf(y.y); r.u[6]=f2bf(y.z); r.u[7]=f2bf(y.w);
    *(uint4*)&dst[o] = r.v;
}

// ---------------------------------------------------------------------------
template<bool F32>
__device__ __forceinline__ uint4 load_cvt(const void* src, size_t off) {
    if constexpr (!F32) {
        return *(const uint4*)((const unsigned short*)src + off);
    } else {
        const float* p = (const float*)src + off;
        const float4 x = *(const float4*)p;
        const float4 y = *(const float4*)(p + 4);
        union { unsigned short u[8]; uint4 v; } r;
        r.u[0]=f2bf(x.x); r.u[1]=f2bf(x.y); r.u[2]=f2bf(x.z); r.u[3]=f2bf(x.w);
        r.u[4]=f2bf(y.x); r.u[5]=f2bf(y.y); r.u[6]=f2bf(y.z); r.u[7]=f2bf(y.w);
        return r.v;
    }
}

// epilogues for the prefix GEMMs
struct EpiBiasF32 {               // gi_img
    float* C; int ldc; const float* bias;
    __device__ void operator()(int m, int n, float v) const {
        C[(size_t)m * ldc + n] = v + bias[n];
    }
};
struct EpiBiasBF16 {              // h0 -> outs rows [0,128)
    ushort_t* C; int ldc; const float* bias;
    __device__ void operator()(int m, int n, float v) const {
        C[(size_t)m * ldc + n] = f2bf(v + bias[n]);
    }
};
struct EpiAdd2D {                 // gi_full = giw + gi_img[b] (+ b_hh for r,z)
    ushort_t* C; int ldc; const float* add; int addld; const float* bhh;
    __device__ void operator()(int m, int n, float v) const {
        const float extra = (n < 1024) ? bhh[n] : 0.f;
        C[(size_t)m * ldc + n] = f2bf(v + add[(size_t)(m & 127) * addld + n] + extra);
    }
};

// ---------------------------------------------------------------------------
// NT GEMM, 128x128 tile, BK=32, 256 thr / 4 waves, bf16 MFMA 16x16x32.
// ---------------------------------------------------------------------------
template<bool AF32, bool BF32, class Epi>
__global__ __launch_bounds__(256) void gemm128(
    const void* __restrict__ A, int lda, const int* __restrict__ gidx,
    const void* __restrict__ Bm, int ldb, int K, Epi epi)
{
    __shared__ ushort_t As[128 * 32];
    __shared__ ushort_t Bs[128 * 32];
    const int tid = threadIdx.x;
    const int m0 = blockIdx.y * 128, n0 = blockIdx.x * 128;
    const int w = tid >> 6, lane = tid & 63, quad = lane >> 4, lr = lane & 15;
    const int srow = tid >> 2, ch = tid & 3;
    const int wm = (w & 1) * 64, wn = (w >> 1) * 64;

    const int ar0 = gidx ? gidx[m0 + srow]      : (m0 + srow);
    const int ar1 = gidx ? gidx[m0 + srow + 64] : (m0 + srow + 64);
    const int br0 = n0 + srow, br1 = n0 + srow + 64;

    f32x4 acc[4][4];
    const f32x4 z4 = {0.f, 0.f, 0.f, 0.f};
#pragma unroll
    for (int i = 0; i < 4; ++i)
#pragma unroll
        for (int j = 0; j < 4; ++j) acc[i][j] = z4;

    for (int k0 = 0; k0 < K; k0 += 32) {
        const uint4 a0 = load_cvt<AF32>(A, (size_t)ar0 * lda + k0 + ch * 8);
        const uint4 a1 = load_cvt<AF32>(A, (size_t)ar1 * lda + k0 + ch * 8);
        const uint4 b0 = load_cvt<BF32>(Bm, (size_t)br0 * ldb + k0 + ch * 8);
        const uint4 b1 = load_cvt<BF32>(Bm, (size_t)br1 * ldb + k0 + ch * 8);
        __syncthreads();
        *(uint4*)&As[(srow)      * 32 + ch * 8] = a0;
        *(uint4*)&As[(srow + 64) * 32 + ch * 8] = a1;
        *(uint4*)&Bs[(srow)      * 32 + ch * 8] = b0;
        *(uint4*)&Bs[(srow + 64) * 32 + ch * 8] = b1;
        __syncthreads();
        short8 af[4], bfr[4];
#pragma unroll
        for (int i = 0; i < 4; ++i) af[i]  = *(const short8*)&As[(wm + i * 16 + lr) * 32 + quad * 8];
#pragma unroll
        for (int j = 0; j < 4; ++j) bfr[j] = *(const short8*)&Bs[(wn + j * 16 + lr) * 32 + quad * 8];
#pragma unroll
        for (int i = 0; i < 4; ++i)
#pragma unroll
            for (int j = 0; j < 4; ++j) acc[i][j] = mfma16(af[i], bfr[j], acc[i][j]);
    }

#pragma unroll
    for (int i = 0; i < 4; ++i)
#pragma unroll
        for (int r = 0; r < 4; ++r) {
            const int m = m0 + wm + i * 16 + quad * 4 + r;
#pragma unroll
            for (int j = 0; j < 4; ++j) {
                const int n = n0 + wn + j * 16 + lr;
                epi(m, n, acc[i][j][r]);
            }
        }
}

// ---------------------------------------------------------------------------
// FUSED recurrence + output projection.
//
// Producers [0,64): g = bid&31, ih = bid>>5. Per step: h A-fragments direct
//   to regs; 48 MFMA; gates (h_old carried in regs, bf16-rounded for bit
//   compat); write-through h store; DISTRIBUTED sync: own 32B-strided flag
//   store (no RMW, no shared counter line), gi(t+1) prefetch issued before
//   the poll, then ALL FOUR waves lane-parallel-poll the 32 same-half flags
//   (__all vote) so each wave proceeds the instant its half is done. Half
//   leaders (bid 0/32) publish a packed half-ready word for consumers.
// Consumers [64,512): persistent; tile tix = t*79+nb, strided by 448. Wait
//   on ONE 8B atomic load of the packed half-ready pair, then 128x128 K=512
//   MFMA GEMM h_{t+1} @ fcw^T, masked transposed store.
// LDS: producer 48*520 ush = 49,920 B -> 2 blocks/CU; grid 512 = 2/CU.
// ---------------------------------------------------------------------------
#define PBS_STR 520
__global__ __launch_bounds__(256, 2) void k_fused(
    const ushort_t* __restrict__ whh_bf,   // (32,48,512)
    const ushort_t* __restrict__ gi_full,  // (31*128,1536)
    const float* __restrict__ b_hh,        // (1536)
    ushort_t* __restrict__ outs,           // (32,128,512)
    const ushort_t* __restrict__ fcw_bf,   // (10112,512)
    const float* __restrict__ fc_b,        // (10000)
    const int* __restrict__ len_i,         // (128)
    float* __restrict__ out,               // (128,31,10000)
    int* __restrict__ sync)                // distributed flags (fcw pad rows)
{
    __shared__ __align__(16) ushort_t sm[48 * PBS_STR];
    const int bid = blockIdx.x;
    const int tid = threadIdx.x;
    const int w = tid >> 6, lane = tid & 63, quad = lane >> 4, lr = lane & 15;

    if (bid < NPROD_) {
        // ---------------- producer ----------------
        __builtin_amdgcn_s_setprio(1);     // latency-critical waves win issue arb
        const int g = bid & 31;
        const int ih = bid >> 5;
        const bool leader = (bid == (ih << 5));   // bid 0 and 32
        ushort_t* Bs = sm;                 // 48 x 520

        const ushort_t* wsrc = whh_bf + (size_t)g * 48 * 512;
        for (int i = tid; i < 48 * 64; i += 256) {
            const int row = i >> 6, c = i & 63;
            *(uint4*)&Bs[row * PBS_STR + c * 8] = *(const uint4*)&wsrc[row * 512 + c * 8];
        }
        const int cg = g * 16 + lr;        // gh col
        const float bhn = b_hh[1024 + cg];
        __syncthreads();

        // h_old carried in registers (bf16-rounded); memory load only for h0
        float hold_reg[4];
        {
            const ushort_t* h0p = outs + (size_t)ih * 64 * 512;
#pragma unroll
            for (int r = 0; r < 4; ++r)
                hold_reg[r] = bf2f(h0p[(size_t)(w * 16 + quad * 4 + r) * 512 + cg]);
        }
        // gi prefetch for step 0
        ushort_t gi0[4], gi1[4], gi2[4];
#pragma unroll
        for (int r = 0; r < 4; ++r) {
            const int b = ih * 64 + w * 16 + quad * 4 + r;
            const ushort_t* p = gi_full + (size_t)b * G3_ + cg;
            gi0[r] = p[0]; gi1[r] = p[512]; gi2[r] = p[1024];
        }

        for (int step = 0; step < T_; ++step) {
            const ushort_t* hsrc = outs + (size_t)step * (128 * 512) + (size_t)ih * 64 * 512;

            // h_t A-fragments: per-lane contiguous 16B chunks straight to regs
            uint4 hv[16];
            const ushort_t* hrow = hsrc + (size_t)(w * 16 + lr) * 512 + quad * 8;
#pragma unroll
            for (int kk = 0; kk < 16; ++kk)
                hv[kk] = *(const uint4*)(hrow + kk * 32);

            f32x4 acc[3];
#pragma unroll
            for (int j = 0; j < 3; ++j) acc[j] = (f32x4){0.f, 0.f, 0.f, 0.f};
#pragma unroll
            for (int kk = 0; kk < 16; ++kk) {
                union { uint4 v; short8 s; } cc; cc.v = hv[kk];
                const short8 af = cc.s;
#pragma unroll
                for (int j = 0; j < 3; ++j) {
                    const short8 bf = *(const short8*)&Bs[(j * 16 + lr) * PBS_STR + kk * 32 + quad * 8];
                    acc[j] = mfma16(af, bf, acc[j]);
                }
            }

            // gates (C-layout: col=lr, row=quad*4+r)
            ushort_t* hdst = outs + (size_t)(step + 1) * (128 * 512);
#pragma unroll
            for (int r = 0; r < 4; ++r) {
                const int b = ih * 64 + w * 16 + quad * 4 + r;
                const float ir  = bf2f(gi0[r]);
                const float iz  = bf2f(gi1[r]);
                const float in_ = bf2f(gi2[r]);
                const float hr = acc[0][r];
                const float hz = acc[1][r];
                const float hn = acc[2][r] + bhn;
                const float rg = 1.f / (1.f + __expf(-(ir + hr)));
                const float zg = 1.f / (1.f + __expf(-(iz + hz)));
                const float nn = tanhf(in_ + rg * hn);
                const float hnew = (1.f - zg) * nn + zg * hold_reg[r];
                const unsigned int hb = (unsigned int)f2bf(hnew);
                hold_reg[r] = bf2f((unsigned short)hb);   // bit-compat carry
                const unsigned int pv = (unsigned int)__shfl_xor((int)hb, 1);
                if ((lr & 1) == 0) {
                    const unsigned int word = hb | (pv << 16);
                    __hip_atomic_store((unsigned int*)&hdst[(size_t)b * 512 + cg], word,
                                       __ATOMIC_RELAXED, __HIP_MEMORY_SCOPE_AGENT);
                }
            }

            // release: drain write-through stores, then distributed signal
            asm volatile("s_waitcnt vmcnt(0)" ::: "memory");
            __syncthreads();          // all 4 waves' stores are at coherence point
            const int tgt = step + 1;
            if (tid == 0)
                __hip_atomic_store(&sync[bid * 8], tgt,
                                   __ATOMIC_RELAXED, __HIP_MEMORY_SCOPE_AGENT);

            // prefetch next step's gi (independent of h) under the wait
            ushort_t ng0[4], ng1[4], ng2[4];
            if (step + 1 < T_) {
                const size_t gb = (size_t)(step + 1) * 128 * G3_;
#pragma unroll
                for (int r = 0; r < 4; ++r) {
                    const int b = ih * 64 + w * 16 + quad * 4 + r;
                    const ushort_t* p = gi_full + gb + (size_t)b * G3_ + cg;
                    ng0[r] = p[0]; ng1[r] = p[512]; ng2[r] = p[1024];
                }
            }
            asm volatile("" ::: "memory");

            // all-wave lane-parallel poll of the 32 same-half flags
            if (step < T_ - 1 || leader) {
                const int* pf = &sync[(ih * 32 + (lane & 31)) * 8];
                int v;
                do {
                    v = __hip_atomic_load(pf, __ATOMIC_RELAXED, __HIP_MEMORY_SCOPE_AGENT);
                } while (!__all(v >= tgt));
            }
            if (leader && tid == 0)
                __hip_atomic_store(&sync[512 + ih], tgt,
                                   __ATOMIC_RELAXED, __HIP_MEMORY_SCOPE_AGENT);
            asm volatile("" ::: "memory");

            if (step + 1 < T_) {
#pragma unroll
                for (int r = 0; r < 4; ++r) { gi0[r] = ng0[r]; gi1[r] = ng1[r]; gi2[r] = ng2[r]; }
            }
        }
    } else {
        // ---------------- persistent consumer (preds tiles) ----------------
        const int cid = bid - NPROD_;
        ushort_t* As = sm;            // 128 x 32
        ushort_t* Bs = sm + 4096;     // 128 x 32
        const int srow = tid >> 2, ch = tid & 3;
        const int wm = (w & 1) * 64, wn = (w >> 1) * 64;
        const ull_t* hready = (const ull_t*)&sync[512];

        for (int tix = cid; tix < NTILE_; tix += NCONS_) {
            const int t = tix / 79;
            const int nb = tix - t * 79;
            const int n0 = nb * 128;

            if (tid == 0) {
                for (;;) {
                    const ull_t hv8 = __hip_atomic_load(hready, __ATOMIC_RELAXED, __HIP_MEMORY_SCOPE_AGENT);
                    const int l0 = (int)(unsigned int)(hv8 & 0xffffffffull);
                    const int l1 = (int)(unsigned int)(hv8 >> 32);
                    if (l0 > t && l1 > t) break;
                    __builtin_amdgcn_s_sleep(8);
                }
            }
            __syncthreads();

            const ushort_t* A = outs + (size_t)(t + 1) * (128 * 512);

            f32x4 acc[4][4];
            const f32x4 z4 = {0.f, 0.f, 0.f, 0.f};
#pragma unroll
            for (int i = 0; i < 4; ++i)
#pragma unroll
                for (int j = 0; j < 4; ++j) acc[i][j] = z4;

            for (int k0 = 0; k0 < 512; k0 += 32) {
                // A rows via L2-bypass 8B atomic loads (written write-through by producers)
                const ull_t a00 = __hip_atomic_load((const ull_t*)&A[(size_t)srow * 512 + k0 + ch * 8],
                                                    __ATOMIC_RELAXED, __HIP_MEMORY_SCOPE_AGENT);
                const ull_t a01 = __hip_atomic_load((const ull_t*)&A[(size_t)srow * 512 + k0 + ch * 8 + 4],
                                                    __ATOMIC_RELAXED, __HIP_MEMORY_SCOPE_AGENT);
                const ull_t a10 = __hip_atomic_load((const ull_t*)&A[(size_t)(srow + 64) * 512 + k0 + ch * 8],
                                                    __ATOMIC_RELAXED, __HIP_MEMORY_SCOPE_AGENT);
                const ull_t a11 = __hip_atomic_load((const ull_t*)&A[(size_t)(srow + 64) * 512 + k0 + ch * 8 + 4],
                                                    __ATOMIC_RELAXED, __HIP_MEMORY_SCOPE_AGENT);
                const uint4 b0 = *(const uint4*)&fcw_bf[(size_t)(n0 + srow)      * 512 + k0 + ch * 8];
                const uint4 b1 = *(const uint4*)&fcw_bf[(size_t)(n0 + srow + 64) * 512 + k0 + ch * 8];
                __syncthreads();
                *(ull_t*)&As[(srow)      * 32 + ch * 8]     = a00;
                *(ull_t*)&As[(srow)      * 32 + ch * 8 + 4] = a01;
                *(ull_t*)&As[(srow + 64) * 32 + ch * 8]     = a10;
                *(ull_t*)&As[(srow + 64) * 32 + ch * 8 + 4] = a11;
                *(uint4*)&Bs[(srow)      * 32 + ch * 8] = b0;
                *(uint4*)&Bs[(srow + 64) * 32 + ch * 8] = b1;
                __syncthreads();
                short8 af[4], bfr[4];
#pragma unroll
                for (int i = 0; i < 4; ++i) af[i]  = *(const short8*)&As[(wm + i * 16 + lr) * 32 + quad * 8];
#pragma unroll
                for (int j = 0; j < 4; ++j) bfr[j] = *(const short8*)&Bs[(wn + j * 16 + lr) * 32 + quad * 8];
#pragma unroll
                for (int i = 0; i < 4; ++i)
#pragma unroll
                    for (int j = 0; j < 4; ++j) acc[i][j] = mfma16(af[i], bfr[j], acc[i][j]);
            }

#pragma unroll
            for (int i = 0; i < 4; ++i)
#pragma unroll
                for (int r = 0; r < 4; ++r) {
                    const int b = wm + i * 16 + quad * 4 + r;
                    const bool act = (t < len_i[b]);
                    const size_t base = (size_t)b * T_ * V_ + (size_t)t * V_;
#pragma unroll
                    for (int j = 0; j < 4; ++j) {
                        const int n = n0 + wn + j * 16 + lr;
                        if (n < V_) out[base + n] = act ? (acc[i][j][r] + fc_b[n]) : 0.f;
                    }
                }
        }
    }
}

// ---------------------------------------------------------------------------
extern "C" void kernel_launch(void* const* d_in, const int* in_sizes, int n_in,
                              void* d_out, int out_size, void* d_ws, size_t ws_size,
                              hipStream_t stream) {
    const float* image_code = (const float*)d_in[0];
    const int*   captions   = (const int*)d_in[1];
    const int*   cap_lens   = (const int*)d_in[2];
    const float* embed_w    = (const float*)d_in[3];
    const float* W_ih       = (const float*)d_in[4];
    const float* W_hh       = (const float*)d_in[5];
    const float* b_ih       = (const float*)d_in[6];
    const float* b_hh       = (const float*)d_in[7];
    const float* fc_w       = (const float*)d_in[8];
    const float* fc_b       = (const float*)d_in[9];
    const float* init_w     = (const float*)d_in[10];
    const float* init_b     = (const float*)d_in[11];

    float* out = (float*)d_out;
    char* ws = (char*)d_ws;
    int*      order   = (int*)(ws + WS_ORDER);
    int*      len_i   = (int*)(ws + WS_LEN);
    int*      tok     = (int*)(ws + WS_TOK);
    int*      bar     = (int*)(ws + WS_BAR);
    float*    gi_img  = (float*)(ws + WS_GIIMG);
    ushort_t* whh_bf  = (ushort_t*)(ws + WS_WHH);
    ushort_t* gi_full = (ushort_t*)(ws + WS_GIFULL);
    ushort_t* outs_bf = (ushort_t*)(ws + WS_OUTS);
    ushort_t* fcw_bf  = (ushort_t*)(ws + WS_FCW);
    // distributed sync flags overlay the zero-padded fcw rows [10108,10112)
    int*      sync    = (int*)(fcw_bf + ((size_t)NPAD_ - 4) * 512);

    // 1) sort + token table + int-ish outputs
    hipLaunchKernelGGL(k_prep, dim3(1), dim3(128), 0, stream,
                       captions, cap_lens, order, len_i, tok, bar,
                       out + (size_t)B_ * T_ * V_);

    // 2) weight conversions (k_cvt_fcw also zeroes the flag region each iter)
    hipLaunchKernelGGL(k_cvt_fcw, dim3((NPAD_ * 64) / 256), dim3(256), 0, stream,
                       fc_w, fcw_bf);
    hipLaunchKernelGGL(k_cvt_whh, dim3((G3_ * H_ / 8) / 256), dim3(256), 0, stream,
                       W_hh, whh_bf);

    // 3) gi_img = ic_s @ W_ih[:, :2048]^T + b_ih
    hipLaunchKernelGGL((gemm128<true, true, EpiBiasF32>), dim3(12, 1), dim3(256), 0, stream,
                       image_code, IC_, order, W_ih, D_, IC_,
                       EpiBiasF32{gi_img, G3_, b_ih});

    // 4) h0 = ic_s @ init_w^T + init_b -> outs rows [0,128)
    hipLaunchKernelGGL((gemm128<true, true, EpiBiasBF16>), dim3(4, 1), dim3(256), 0, stream,
                       image_code, IC_, order, init_w, IC_, IC_,
                       EpiBiasBF16{outs_bf, H_, init_b});

    // 5) gi_full = emb @ W_ih[:, 2048:]^T + gi_img[b] + b_hh(r,z)
    hipLaunchKernelGGL((gemm128<true, true, EpiAdd2D>), dim3(12, 31), dim3(256), 0, stream,
                       embed_w, WD_, tok, W_ih + IC_, D_, WD_,
                       EpiAdd2D{gi_full, G3_, gi_img, G3_, b_hh});

    // 6) fused persistent recurrence + streaming output projection
    hipLaunchKernelGGL(k_fused, dim3(NPROD_ + NCONS_), dim3(256), 0, stream,
                       whh_bf, gi_full, b_hh, outs_bf,
                       fcw_bf, fc_b, len_i, out, sync);
}

// Round 3
// 648.546 us; speedup vs baseline: 1.4801x; 1.0258x over previous
//
#include <hip/hip_runtime.h>
#include <math.h>

#define B_   128
#define L_   32
#define T_   31
#define V_   10000
#define IC_  2048
#define WD_  512
#define H_   512
#define D_   2560
#define G3_  1536   // 3*H
#define NPAD_ 10112 // V padded to 79*128
#define NTILE_ (79 * 31)          // consumer tiles (t, nb)
#define NPROD_ 64                 // producer blocks
#define NCONS_ 448                // persistent consumer blocks (64+448=512 = 2/CU)

typedef short short8 __attribute__((ext_vector_type(8)));
typedef float f32x4  __attribute__((ext_vector_type(4)));
typedef unsigned short ushort_t;
typedef unsigned long long ull_t;

__device__ __forceinline__ unsigned short f2bf(float f) {
    unsigned int u = __builtin_bit_cast(unsigned int, f);
    unsigned int r = (u + 0x7FFFu + ((u >> 16) & 1u)) >> 16;
    return (unsigned short)r;
}
__device__ __forceinline__ float bf2f(unsigned short h) {
    unsigned int u = ((unsigned int)h) << 16;
    return __builtin_bit_cast(float, u);
}
__device__ __forceinline__ f32x4 mfma16(short8 a, short8 b, f32x4 c) {
    return __builtin_amdgcn_mfma_f32_16x16x32_bf16(a, b, c, 0, 0, 0);
}

// ---- workspace layout (byte offsets) ----
#define WS_ORDER  0          // int[128]
#define WS_LEN    512        // int[128]
#define WS_TOK    1024       // int[3968] -> ends 16896
#define WS_BAR    16896      // int (legacy, zeroed, unused by k_fused)
#define WS_GIIMG  16960      // float[128*1536]          -> ends 803392
#define WS_WHH    803392     // bf16 [32][48][512] perm  -> ends 2376256
#define WS_GIFULL 2376256    // bf16 [3968*1536]         -> ends 14565952
#define WS_OUTS   14565952   // bf16 [32*128*512]        -> ends 18760256
#define WS_FCW    18760256   // bf16 [10112*512]         -> ends 29114944
// sync flags live inside the zero-padded fcw rows [10108,10112) (4096 B):
//   - zeroed every iteration by k_cvt_fcw (rows >= V_ write 0)
//   - read as B-operand only for output cols n >= V_, which are masked
//   int sync[i*8]          : per-producer flag i in [0,64), value = step+1
//   int sync[768 + k*16+ih]: half-ready replica k in [0,8) (8B-pair loadable)

// ---------------------------------------------------------------------------
__global__ void k_prep(const int* __restrict__ captions,
                       const int* __restrict__ cap_lens,
                       int* __restrict__ order,
                       int* __restrict__ len_i,
                       int* __restrict__ tok,
                       int* __restrict__ bar,
                       float* __restrict__ out_tail) {
    __shared__ int s_len[B_];
    __shared__ int s_ord[B_];
    const int tid = threadIdx.x;
    if (tid == 0) *bar = 0;
    if (tid < B_) s_len[tid] = cap_lens[tid];
    __syncthreads();
    if (tid < B_) {
        const int myl = s_len[tid];
        int rank = 0;
        for (int k = 0; k < B_; ++k) {
            const int lk = s_len[k];
            if (lk > myl || (lk == myl && k < tid)) rank++;
        }
        s_ord[rank] = tid;
    }
    __syncthreads();
    if (tid < B_) {
        const int o = s_ord[tid];
        order[tid] = o;
        const int ln = s_len[o] - 1;
        len_i[tid] = ln;
        out_tail[B_ * L_ + tid]      = (float)ln;
        out_tail[B_ * L_ + B_ + tid] = (float)o;
    }
    __syncthreads();
    for (int i = tid; i < B_ * L_; i += blockDim.x) {
        const int b = i / L_, l = i % L_;
        const int c = captions[s_ord[b] * L_ + l];
        out_tail[i] = (float)c;
        if (l < T_) tok[l * B_ + b] = c;
    }
}

// fc_w (10000x512 f32) -> bf16 padded to 10112 rows (zero tail; also zeroes flags)
__global__ void k_cvt_fcw(const float* __restrict__ src, ushort_t* __restrict__ dst) {
    const int idx = blockIdx.x * 256 + threadIdx.x;
    const int row = idx >> 6;
    const int ch  = idx & 63;
    union { unsigned short u[8]; uint4 v; } r;
    if (row < V_) {
        const float* p = src + (size_t)row * 512 + ch * 8;
        const float4 x = *(const float4*)p;
        const float4 y = *(const float4*)(p + 4);
        r.u[0]=f2bf(x.x); r.u[1]=f2bf(x.y); r.u[2]=f2bf(x.z); r.u[3]=f2bf(x.w);
        r.u[4]=f2bf(y.x); r.u[5]=f2bf(y.y); r.u[6]=f2bf(y.z); r.u[7]=f2bf(y.w);
    } else {
        r.v = make_uint4(0, 0, 0, 0);
    }
    *(uint4*)&dst[(size_t)row * 512 + ch * 8] = r.v;
}

// W_hh (1536x512 f32) -> bf16, permuted into 32 slices of 48x512:
// slice g, local row j (= gate*16 + c) <- source row gate*512 + g*16 + c
__global__ void k_cvt_whh(const float* __restrict__ whh, ushort_t* __restrict__ dst) {
    const int idx = blockIdx.x * 256 + threadIdx.x;
    const size_t o = (size_t)idx * 8;
    const int g = (int)(o / (48 * 512));
    const int rem = (int)(o % (48 * 512));
    const int j = rem >> 9;
    const int k = rem & 511;
    const int srow = (j >> 4) * 512 + g * 16 + (j & 15);
    const float* p = whh + (size_t)srow * 512 + k;
    const float4 x = *(const float4*)p;
    const float4 y = *(const float4*)(p + 4);
    union { unsigned short u[8]; uint4 v; } r;
    r.u[0]=f2bf(x.x); r.u[1]=f2bf(x.y); r.u[2]=f2bf(x.z); r.u[3]=f2bf(x.w);
    r.u[4]=f2bf(y.x); r.u[5]=f2bf(y.y); r.u[6]=f2bf(y.z); r.u[7]=f2bf(y.w);
    *(uint4*)&dst[o] = r.v;
}

// ---------------------------------------------------------------------------
template<bool F32>
__device__ __forceinline__ uint4 load_cvt(const void* src, size_t off) {
    if constexpr (!F32) {
        return *(const uint4*)((const unsigned short*)src + off);
    } else {
        const float* p = (const float*)src + off;
        const float4 x = *(const float4*)p;
        const float4 y = *(const float4*)(p + 4);
        union { unsigned short u[8]; uint4 v; } r;
        r.u[0]=f2bf(x.x); r.u[1]=f2bf(x.y); r.u[2]=f2bf(x.z); r.u[3]=f2bf(x.w);
        r.u[4]=f2bf(y.x); r.u[5]=f2bf(y.y); r.u[6]=f2bf(y.z); r.u[7]=f2bf(y.w);
        return r.v;
    }
}

// epilogues for the prefix GEMMs
struct EpiBiasF32 {               // gi_img
    float* C; int ldc; const float* bias;
    __device__ void operator()(int m, int n, float v) const {
        C[(size_t)m * ldc + n] = v + bias[n];
    }
};
struct EpiBiasBF16 {              // h0 -> outs rows [0,128)
    ushort_t* C; int ldc; const float* bias;
    __device__ void operator()(int m, int n, float v) const {
        C[(size_t)m * ldc + n] = f2bf(v + bias[n]);
    }
};
struct EpiAdd2D {                 // gi_full = giw + gi_img[b] (+ b_hh for r,z)
    ushort_t* C; int ldc; const float* add; int addld; const float* bhh;
    __device__ void operator()(int m, int n, float v) const {
        const float extra = (n < 1024) ? bhh[n] : 0.f;
        C[(size_t)m * ldc + n] = f2bf(v + add[(size_t)(m & 127) * addld + n] + extra);
    }
};

// ---------------------------------------------------------------------------
// NT GEMM, 128x128 tile, BK=32, 256 thr / 4 waves, bf16 MFMA 16x16x32.
// ---------------------------------------------------------------------------
template<bool AF32, bool BF32, class Epi>
__global__ __launch_bounds__(256) void gemm128(
    const void* __restrict__ A, int lda, const int* __restrict__ gidx,
    const void* __restrict__ Bm, int ldb, int K, Epi epi)
{
    __shared__ ushort_t As[128 * 32];
    __shared__ ushort_t Bs[128 * 32];
    const int tid = threadIdx.x;
    const int m0 = blockIdx.y * 128, n0 = blockIdx.x * 128;
    const int w = tid >> 6, lane = tid & 63, quad = lane >> 4, lr = lane & 15;
    const int srow = tid >> 2, ch = tid & 3;
    const int wm = (w & 1) * 64, wn = (w >> 1) * 64;

    const int ar0 = gidx ? gidx[m0 + srow]      : (m0 + srow);
    const int ar1 = gidx ? gidx[m0 + srow + 64] : (m0 + srow + 64);
    const int br0 = n0 + srow, br1 = n0 + srow + 64;

    f32x4 acc[4][4];
    const f32x4 z4 = {0.f, 0.f, 0.f, 0.f};
#pragma unroll
    for (int i = 0; i < 4; ++i)
#pragma unroll
        for (int j = 0; j < 4; ++j) acc[i][j] = z4;

    for (int k0 = 0; k0 < K; k0 += 32) {
        const uint4 a0 = load_cvt<AF32>(A, (size_t)ar0 * lda + k0 + ch * 8);
        const uint4 a1 = load_cvt<AF32>(A, (size_t)ar1 * lda + k0 + ch * 8);
        const uint4 b0 = load_cvt<BF32>(Bm, (size_t)br0 * ldb + k0 + ch * 8);
        const uint4 b1 = load_cvt<BF32>(Bm, (size_t)br1 * ldb + k0 + ch * 8);
        __syncthreads();
        *(uint4*)&As[(srow)      * 32 + ch * 8] = a0;
        *(uint4*)&As[(srow + 64) * 32 + ch * 8] = a1;
        *(uint4*)&Bs[(srow)      * 32 + ch * 8] = b0;
        *(uint4*)&Bs[(srow + 64) * 32 + ch * 8] = b1;
        __syncthreads();
        short8 af[4], bfr[4];
#pragma unroll
        for (int i = 0; i < 4; ++i) af[i]  = *(const short8*)&As[(wm + i * 16 + lr) * 32 + quad * 8];
#pragma unroll
        for (int j = 0; j < 4; ++j) bfr[j] = *(const short8*)&Bs[(wn + j * 16 + lr) * 32 + quad * 8];
#pragma unroll
        for (int i = 0; i < 4; ++i)
#pragma unroll
            for (int j = 0; j < 4; ++j) acc[i][j] = mfma16(af[i], bfr[j], acc[i][j]);
    }

#pragma unroll
    for (int i = 0; i < 4; ++i)
#pragma unroll
        for (int r = 0; r < 4; ++r) {
            const int m = m0 + wm + i * 16 + quad * 4 + r;
#pragma unroll
            for (int j = 0; j < 4; ++j) {
                const int n = n0 + wn + j * 16 + lr;
                epi(m, n, acc[i][j][r]);
            }
        }
}

// ---------------------------------------------------------------------------
// FUSED recurrence + output projection.
//
// Producers [0,64): g = bid&31, ih = bid>>5. Per step: h A-fragments direct
//   to regs; 48 MFMA; gates (h_old carried in regs); write-through h store;
//   distributed per-producer flags. POLL DISCIPLINE (R3): only wave 0 polls
//   the 32 same-half flags, with s_sleep(1) backoff, then a barrier releases
//   the other 3 waves -- cuts the L3 flag-line request storm ~10-40x so the
//   last flag store and its observation aren't queued behind reader floods.
//   Half leaders (bid 0/32) publish 8 REPLICAS of the half-ready pair.
// Consumers [64,512): persistent; tile tix = t*79+nb, strided by 448. Poll
//   replica (cid&7) with s_sleep(16) backoff; A rows read as PLAIN cached
//   uint4 (L2-absorbed; 79 tiles/step re-read the same 128KB h tile), then
//   128x128 K=512 MFMA GEMM h_{t+1} @ fcw^T, masked transposed store.
// LDS: producer 48*520 ush = 49,920 B -> 2 blocks/CU; grid 512 = 2/CU.
// ---------------------------------------------------------------------------
#define PBS_STR 520
__global__ __launch_bounds__(256, 2) void k_fused(
    const ushort_t* __restrict__ whh_bf,   // (32,48,512)
    const ushort_t* __restrict__ gi_full,  // (31*128,1536)
    const float* __restrict__ b_hh,        // (1536)
    ushort_t* __restrict__ outs,           // (32,128,512)
    const ushort_t* __restrict__ fcw_bf,   // (10112,512)
    const float* __restrict__ fc_b,        // (10000)
    const int* __restrict__ len_i,         // (128)
    float* __restrict__ out,               // (128,31,10000)
    int* __restrict__ sync)                // distributed flags (fcw pad rows)
{
    __shared__ __align__(16) ushort_t sm[48 * PBS_STR];
    const int bid = blockIdx.x;
    const int tid = threadIdx.x;
    const int w = tid >> 6, lane = tid & 63, quad = lane >> 4, lr = lane & 15;

    if (bid < NPROD_) {
        // ---------------- producer ----------------
        __builtin_amdgcn_s_setprio(1);     // latency-critical waves win issue arb
        const int g = bid & 31;
        const int ih = bid >> 5;
        const bool leader = (bid == (ih << 5));   // bid 0 and 32
        ushort_t* Bs = sm;                 // 48 x 520

        const ushort_t* wsrc = whh_bf + (size_t)g * 48 * 512;
        for (int i = tid; i < 48 * 64; i += 256) {
            const int row = i >> 6, c = i & 63;
            *(uint4*)&Bs[row * PBS_STR + c * 8] = *(const uint4*)&wsrc[row * 512 + c * 8];
        }
        const int cg = g * 16 + lr;        // gh col
        const float bhn = b_hh[1024 + cg];
        __syncthreads();

        // h_old carried in registers (bf16-rounded); memory load only for h0
        float hold_reg[4];
        {
            const ushort_t* h0p = outs + (size_t)ih * 64 * 512;
#pragma unroll
            for (int r = 0; r < 4; ++r)
                hold_reg[r] = bf2f(h0p[(size_t)(w * 16 + quad * 4 + r) * 512 + cg]);
        }
        // gi prefetch for step 0
        ushort_t gi0[4], gi1[4], gi2[4];
#pragma unroll
        for (int r = 0; r < 4; ++r) {
            const int b = ih * 64 + w * 16 + quad * 4 + r;
            const ushort_t* p = gi_full + (size_t)b * G3_ + cg;
            gi0[r] = p[0]; gi1[r] = p[512]; gi2[r] = p[1024];
        }

        for (int step = 0; step < T_; ++step) {
            const ushort_t* hsrc = outs + (size_t)step * (128 * 512) + (size_t)ih * 64 * 512;

            // h_t A-fragments: per-lane contiguous 16B chunks straight to regs
            uint4 hv[16];
            const ushort_t* hrow = hsrc + (size_t)(w * 16 + lr) * 512 + quad * 8;
#pragma unroll
            for (int kk = 0; kk < 16; ++kk)
                hv[kk] = *(const uint4*)(hrow + kk * 32);

            f32x4 acc[3];
#pragma unroll
            for (int j = 0; j < 3; ++j) acc[j] = (f32x4){0.f, 0.f, 0.f, 0.f};
#pragma unroll
            for (int kk = 0; kk < 16; ++kk) {
                union { uint4 v; short8 s; } cc; cc.v = hv[kk];
                const short8 af = cc.s;
#pragma unroll
                for (int j = 0; j < 3; ++j) {
                    const short8 bf = *(const short8*)&Bs[(j * 16 + lr) * PBS_STR + kk * 32 + quad * 8];
                    acc[j] = mfma16(af, bf, acc[j]);
                }
            }

            // gates (C-layout: col=lr, row=quad*4+r)
            ushort_t* hdst = outs + (size_t)(step + 1) * (128 * 512);
#pragma unroll
            for (int r = 0; r < 4; ++r) {
                const int b = ih * 64 + w * 16 + quad * 4 + r;
                const float ir  = bf2f(gi0[r]);
                const float iz  = bf2f(gi1[r]);
                const float in_ = bf2f(gi2[r]);
                const float hr = acc[0][r];
                const float hz = acc[1][r];
                const float hn = acc[2][r] + bhn;
                const float rg = 1.f / (1.f + __expf(-(ir + hr)));
                const float zg = 1.f / (1.f + __expf(-(iz + hz)));
                const float nn = tanhf(in_ + rg * hn);
                const float hnew = (1.f - zg) * nn + zg * hold_reg[r];
                const unsigned int hb = (unsigned int)f2bf(hnew);
                hold_reg[r] = bf2f((unsigned short)hb);   // bit-compat carry
                const unsigned int pv = (unsigned int)__shfl_xor((int)hb, 1);
                if ((lr & 1) == 0) {
                    const unsigned int word = hb | (pv << 16);
                    __hip_atomic_store((unsigned int*)&hdst[(size_t)b * 512 + cg], word,
                                       __ATOMIC_RELAXED, __HIP_MEMORY_SCOPE_AGENT);
                }
            }

            // release: drain write-through stores, then distributed signal
            asm volatile("s_waitcnt vmcnt(0)" ::: "memory");
            __syncthreads();          // all 4 waves' stores are at coherence point
            const int tgt = step + 1;
            if (tid == 0)
                __hip_atomic_store(&sync[bid * 8], tgt,
                                   __ATOMIC_RELAXED, __HIP_MEMORY_SCOPE_AGENT);

            // prefetch next step's gi (independent of h) under the wait
            ushort_t ng0[4], ng1[4], ng2[4];
            if (step + 1 < T_) {
                const size_t gb = (size_t)(step + 1) * 128 * G3_;
#pragma unroll
                for (int r = 0; r < 4; ++r) {
                    const int b = ih * 64 + w * 16 + quad * 4 + r;
                    const ushort_t* p = gi_full + gb + (size_t)b * G3_ + cg;
                    ng0[r] = p[0]; ng1[r] = p[512]; ng2[r] = p[1024];
                }
            }
            asm volatile("" ::: "memory");

            // wave 0 only polls the 32 same-half flags, with backoff
            if (w == 0 && (step < T_ - 1 || leader)) {
                const int* pf = &sync[(ih * 32 + (lane & 31)) * 8];
                for (;;) {
                    const int v = __hip_atomic_load(pf, __ATOMIC_RELAXED, __HIP_MEMORY_SCOPE_AGENT);
                    if (__all(v >= tgt)) break;
                    __builtin_amdgcn_s_sleep(1);
                }
                if (leader && lane == 0) {
#pragma unroll
                    for (int k = 0; k < 8; ++k)
                        __hip_atomic_store(&sync[768 + k * 16 + ih], tgt,
                                           __ATOMIC_RELAXED, __HIP_MEMORY_SCOPE_AGENT);
                }
            }
            __syncthreads();          // release waves 1-3
            asm volatile("" ::: "memory");

            if (step + 1 < T_) {
#pragma unroll
                for (int r = 0; r < 4; ++r) { gi0[r] = ng0[r]; gi1[r] = ng1[r]; gi2[r] = ng2[r]; }
            }
        }
    } else {
        // ---------------- persistent consumer (preds tiles) ----------------
        const int cid = bid - NPROD_;
        ushort_t* As = sm;            // 128 x 32
        ushort_t* Bs = sm + 4096;     // 128 x 32
        const int srow = tid >> 2, ch = tid & 3;
        const int wm = (w & 1) * 64, wn = (w >> 1) * 64;
        const ull_t* hready = (const ull_t*)&sync[768 + (cid & 7) * 16];

        for (int tix = cid; tix < NTILE_; tix += NCONS_) {
            const int t = tix / 79;
            const int nb = tix - t * 79;
            const int n0 = nb * 128;

            if (tid == 0) {
                for (;;) {
                    const ull_t hv8 = __hip_atomic_load(hready, __ATOMIC_RELAXED, __HIP_MEMORY_SCOPE_AGENT);
                    const int l0 = (int)(unsigned int)(hv8 & 0xffffffffull);
                    const int l1 = (int)(unsigned int)(hv8 >> 32);
                    if (l0 > t && l1 > t) break;
                    __builtin_amdgcn_s_sleep(16);
                }
            }
            __syncthreads();

            const ushort_t* A = outs + (size_t)(t + 1) * (128 * 512);

            f32x4 acc[4][4];
            const f32x4 z4 = {0.f, 0.f, 0.f, 0.f};
#pragma unroll
            for (int i = 0; i < 4; ++i)
#pragma unroll
                for (int j = 0; j < 4; ++j) acc[i][j] = z4;

            for (int k0 = 0; k0 < 512; k0 += 32) {
                // A rows as plain cached loads (L2-absorbed; flag-gated so fresh)
                const uint4 a0 = *(const uint4*)&A[(size_t)srow * 512 + k0 + ch * 8];
                const uint4 a1 = *(const uint4*)&A[(size_t)(srow + 64) * 512 + k0 + ch * 8];
                const uint4 b0 = *(const uint4*)&fcw_bf[(size_t)(n0 + srow)      * 512 + k0 + ch * 8];
                const uint4 b1 = *(const uint4*)&fcw_bf[(size_t)(n0 + srow + 64) * 512 + k0 + ch * 8];
                __syncthreads();
                *(uint4*)&As[(srow)      * 32 + ch * 8] = a0;
                *(uint4*)&As[(srow + 64) * 32 + ch * 8] = a1;
                *(uint4*)&Bs[(srow)      * 32 + ch * 8] = b0;
                *(uint4*)&Bs[(srow + 64) * 32 + ch * 8] = b1;
                __syncthreads();
                short8 af[4], bfr[4];
#pragma unroll
                for (int i = 0; i < 4; ++i) af[i]  = *(const short8*)&As[(wm + i * 16 + lr) * 32 + quad * 8];
#pragma unroll
                for (int j = 0; j < 4; ++j) bfr[j] = *(const short8*)&Bs[(wn + j * 16 + lr) * 32 + quad * 8];
#pragma unroll
                for (int i = 0; i < 4; ++i)
#pragma unroll
                    for (int j = 0; j < 4; ++j) acc[i][j] = mfma16(af[i], bfr[j], acc[i][j]);
            }

#pragma unroll
            for (int i = 0; i < 4; ++i)
#pragma unroll
                for (int r = 0; r < 4; ++r) {
                    const int b = wm + i * 16 + quad * 4 + r;
                    const bool act = (t < len_i[b]);
                    const size_t base = (size_t)b * T_ * V_ + (size_t)t * V_;
#pragma unroll
                    for (int j = 0; j < 4; ++j) {
                        const int n = n0 + wn + j * 16 + lr;
                        if (n < V_) out[base + n] = act ? (acc[i][j][r] + fc_b[n]) : 0.f;
                    }
                }
        }
    }
}

// ---------------------------------------------------------------------------
extern "C" void kernel_launch(void* const* d_in, const int* in_sizes, int n_in,
                              void* d_out, int out_size, void* d_ws, size_t ws_size,
                              hipStream_t stream) {
    const float* image_code = (const float*)d_in[0];
    const int*   captions   = (const int*)d_in[1];
    const int*   cap_lens   = (const int*)d_in[2];
    const float* embed_w    = (const float*)d_in[3];
    const float* W_ih       = (const float*)d_in[4];
    const float* W_hh       = (const float*)d_in[5];
    const float* b_ih       = (const float*)d_in[6];
    const float* b_hh       = (const float*)d_in[7];
    const float* fc_w       = (const float*)d_in[8];
    const float* fc_b       = (const float*)d_in[9];
    const float* init_w     = (const float*)d_in[10];
    const float* init_b     = (const float*)d_in[11];

    float* out = (float*)d_out;
    char* ws = (char*)d_ws;
    int*      order   = (int*)(ws + WS_ORDER);
    int*      len_i   = (int*)(ws + WS_LEN);
    int*      tok     = (int*)(ws + WS_TOK);
    int*      bar     = (int*)(ws + WS_BAR);
    float*    gi_img  = (float*)(ws + WS_GIIMG);
    ushort_t* whh_bf  = (ushort_t*)(ws + WS_WHH);
    ushort_t* gi_full = (ushort_t*)(ws + WS_GIFULL);
    ushort_t* outs_bf = (ushort_t*)(ws + WS_OUTS);
    ushort_t* fcw_bf  = (ushort_t*)(ws + WS_FCW);
    // distributed sync flags overlay the zero-padded fcw rows [10108,10112)
    int*      sync    = (int*)(fcw_bf + ((size_t)NPAD_ - 4) * 512);

    // 1) sort + token table + int-ish outputs
    hipLaunchKernelGGL(k_prep, dim3(1), dim3(128), 0, stream,
                       captions, cap_lens, order, len_i, tok, bar,
                       out + (size_t)B_ * T_ * V_);

    // 2) weight conversions (k_cvt_fcw also zeroes the flag region each iter)
    hipLaunchKernelGGL(k_cvt_fcw, dim3((NPAD_ * 64) / 256), dim3(256), 0, stream,
                       fc_w, fcw_bf);
    hipLaunchKernelGGL(k_cvt_whh, dim3((G3_ * H_ / 8) / 256), dim3(256), 0, stream,
                       W_hh, whh_bf);

    // 3) gi_img = ic_s @ W_ih[:, :2048]^T + b_ih
    hipLaunchKernelGGL((gemm128<true, true, EpiBiasF32>), dim3(12, 1), dim3(256), 0, stream,
                       image_code, IC_, order, W_ih, D_, IC_,
                       EpiBiasF32{gi_img, G3_, b_ih});

    // 4) h0 = ic_s @ init_w^T + init_b -> outs rows [0,128)
    hipLaunchKernelGGL((gemm128<true, true, EpiBiasBF16>), dim3(4, 1), dim3(256), 0, stream,
                       image_code, IC_, order, init_w, IC_, IC_,
                       EpiBiasBF16{outs_bf, H_, init_b});

    // 5) gi_full = emb @ W_ih[:, 2048:]^T + gi_img[b] + b_hh(r,z)
    hipLaunchKernelGGL((gemm128<true, true, EpiAdd2D>), dim3(12, 31), dim3(256), 0, stream,
                       embed_w, WD_, tok, W_ih + IC_, D_, WD_,
                       EpiAdd2D{gi_full, G3_, gi_img, G3_, b_hh});

    // 6) fused persistent recurrence + streaming output projection
    hipLaunchKernelGGL(k_fused, dim3(NPROD_ + NCONS_), dim3(256), 0, stream,
                       whh_bf, gi_full, b_hh, outs_bf,
                       fcw_bf, fc_b, len_i, out, sync);
}

// Round 4
// 538.037 us; speedup vs baseline: 1.7842x; 1.2054x over previous
//
#include <hip/hip_runtime.h>
#include <math.h>

#define B_   128
#define L_   32
#define T_   31
#define V_   10000
#define IC_  2048
#define WD_  512
#define H_   512
#define D_   2560
#define G3_  1536   // 3*H
#define NPAD_ 10112 // V padded to 79*128
#define NPROD_ 64                 // producer blocks
#define NCONS_ 395                // consumer blocks = 79 nb-slots x 5 teams
#define NTEAM_ 5

typedef short short8 __attribute__((ext_vector_type(8)));
typedef float f32x4  __attribute__((ext_vector_type(4)));
typedef unsigned short ushort_t;
typedef unsigned long long ull_t;

__device__ __forceinline__ unsigned short f2bf(float f) {
    unsigned int u = __builtin_bit_cast(unsigned int, f);
    unsigned int r = (u + 0x7FFFu + ((u >> 16) & 1u)) >> 16;
    return (unsigned short)r;
}
__device__ __forceinline__ float bf2f(unsigned short h) {
    unsigned int u = ((unsigned int)h) << 16;
    return __builtin_bit_cast(float, u);
}
__device__ __forceinline__ f32x4 mfma16(short8 a, short8 b, f32x4 c) {
    return __builtin_amdgcn_mfma_f32_16x16x32_bf16(a, b, c, 0, 0, 0);
}

// ---- workspace layout (byte offsets) ----
#define WS_ORDER  0          // int[128]
#define WS_LEN    512        // int[128]
#define WS_TOK    1024       // int[3968] -> ends 16896
#define WS_BAR    16896      // int (legacy, zeroed, unused by k_fused)
#define WS_GIIMG  16960      // float[128*1536]          -> ends 803392
#define WS_WHH    803392     // bf16 [32][48][512] perm  -> ends 2376256
#define WS_GIFULL 2376256    // bf16 [3968*1536]         -> ends 14565952
#define WS_OUTS   14565952   // bf16 [32*128*512]        -> ends 18760256
#define WS_FCW    18760256   // bf16 [10112*512]         -> ends 29114944
// sync flags live inside the zero-padded fcw rows [10108,10112) (4096 B):
//   - zeroed every iteration by k_cvt_fcw (rows >= V_ write 0)
//   - read as B-operand only for output cols n >= V_, which are masked
//   int sync[i*8]          : per-producer flag i in [0,64), value = step+1
//   int sync[768 + k*16+ih]: half-ready replica k in [0,8) (8B-pair loadable)

// ---------------------------------------------------------------------------
__global__ void k_prep(const int* __restrict__ captions,
                       const int* __restrict__ cap_lens,
                       int* __restrict__ order,
                       int* __restrict__ len_i,
                       int* __restrict__ tok,
                       int* __restrict__ bar,
                       float* __restrict__ out_tail) {
    __shared__ int s_len[B_];
    __shared__ int s_ord[B_];
    const int tid = threadIdx.x;
    if (tid == 0) *bar = 0;
    if (tid < B_) s_len[tid] = cap_lens[tid];
    __syncthreads();
    if (tid < B_) {
        const int myl = s_len[tid];
        int rank = 0;
        for (int k = 0; k < B_; ++k) {
            const int lk = s_len[k];
            if (lk > myl || (lk == myl && k < tid)) rank++;
        }
        s_ord[rank] = tid;
    }
    __syncthreads();
    if (tid < B_) {
        const int o = s_ord[tid];
        order[tid] = o;
        const int ln = s_len[o] - 1;
        len_i[tid] = ln;
        out_tail[B_ * L_ + tid]      = (float)ln;
        out_tail[B_ * L_ + B_ + tid] = (float)o;
    }
    __syncthreads();
    for (int i = tid; i < B_ * L_; i += blockDim.x) {
        const int b = i / L_, l = i % L_;
        const int c = captions[s_ord[b] * L_ + l];
        out_tail[i] = (float)c;
        if (l < T_) tok[l * B_ + b] = c;
    }
}

// fc_w (10000x512 f32) -> bf16 padded to 10112 rows (zero tail; also zeroes flags)
__global__ void k_cvt_fcw(const float* __restrict__ src, ushort_t* __restrict__ dst) {
    const int idx = blockIdx.x * 256 + threadIdx.x;
    const int row = idx >> 6;
    const int ch  = idx & 63;
    union { unsigned short u[8]; uint4 v; } r;
    if (row < V_) {
        const float* p = src + (size_t)row * 512 + ch * 8;
        const float4 x = *(const float4*)p;
        const float4 y = *(const float4*)(p + 4);
        r.u[0]=f2bf(x.x); r.u[1]=f2bf(x.y); r.u[2]=f2bf(x.z); r.u[3]=f2bf(x.w);
        r.u[4]=f2bf(y.x); r.u[5]=f2bf(y.y); r.u[6]=f2bf(y.z); r.u[7]=f2bf(y.w);
    } else {
        r.v = make_uint4(0, 0, 0, 0);
    }
    *(uint4*)&dst[(size_t)row * 512 + ch * 8] = r.v;
}

// W_hh (1536x512 f32) -> bf16, permuted into 32 slices of 48x512:
// slice g, local row j (= gate*16 + c) <- source row gate*512 + g*16 + c
__global__ void k_cvt_whh(const float* __restrict__ whh, ushort_t* __restrict__ dst) {
    const int idx = blockIdx.x * 256 + threadIdx.x;
    const size_t o = (size_t)idx * 8;
    const int g = (int)(o / (48 * 512));
    const int rem = (int)(o % (48 * 512));
    const int j = rem >> 9;
    const int k = rem & 511;
    const int srow = (j >> 4) * 512 + g * 16 + (j & 15);
    const float* p = whh + (size_t)srow * 512 + k;
    const float4 x = *(const float4*)p;
    const float4 y = *(const float4*)(p + 4);
    union { unsigned short u[8]; uint4 v; } r;
    r.u[0]=f2bf(x.x); r.u[1]=f2bf(x.y); r.u[2]=f2bf(x.z); r.u[3]=f2bf(x.w);
    r.u[4]=f2bf(y.x); r.u[5]=f2bf(y.y); r.u[6]=f2bf(y.z); r.u[7]=f2bf(y.w);
    *(uint4*)&dst[o] = r.v;
}

// ---------------------------------------------------------------------------
template<bool F32>
__device__ __forceinline__ uint4 load_cvt(const void* src, size_t off) {
    if constexpr (!F32) {
        return *(const uint4*)((const unsigned short*)src + off);
    } else {
        const float* p = (const float*)src + off;
        const float4 x = *(const float4*)p;
        const float4 y = *(const float4*)(p + 4);
        union { unsigned short u[8]; uint4 v; } r;
        r.u[0]=f2bf(x.x); r.u[1]=f2bf(x.y); r.u[2]=f2bf(x.z); r.u[3]=f2bf(x.w);
        r.u[4]=f2bf(y.x); r.u[5]=f2bf(y.y); r.u[6]=f2bf(y.z); r.u[7]=f2bf(y.w);
        return r.v;
    }
}

struct EpiAdd2D {                 // gi_full = giw + gi_img[b] (+ b_hh for r,z)
    ushort_t* C; int ldc; const float* add; int addld; const float* bhh;
    __device__ void operator()(int m, int n, float v) const {
        const float extra = (n < 1024) ? bhh[n] : 0.f;
        C[(size_t)m * ldc + n] = f2bf(v + add[(size_t)(m & 127) * addld + n] + extra);
    }
};

// ---------------------------------------------------------------------------
// NT GEMM, 128x128 tile, BK=32, 256 thr / 4 waves, bf16 MFMA 16x16x32.
// Double-buffered: next K-chunk prefetched into regs before the MFMA block
// so global-load latency hides under compute (the small grids here are
// latency-bound, not BW-bound).
// ---------------------------------------------------------------------------
template<bool AF32, bool BF32, class Epi>
__global__ __launch_bounds__(256) void gemm128(
    const void* __restrict__ A, int lda, const int* __restrict__ gidx,
    const void* __restrict__ Bm, int ldb, int K, Epi epi)
{
    __shared__ ushort_t As[128 * 32];
    __shared__ ushort_t Bs[128 * 32];
    const int tid = threadIdx.x;
    const int m0 = blockIdx.y * 128, n0 = blockIdx.x * 128;
    const int w = tid >> 6, lane = tid & 63, quad = lane >> 4, lr = lane & 15;
    const int srow = tid >> 2, ch = tid & 3;
    const int wm = (w & 1) * 64, wn = (w >> 1) * 64;

    const int ar0 = gidx ? gidx[m0 + srow]      : (m0 + srow);
    const int ar1 = gidx ? gidx[m0 + srow + 64] : (m0 + srow + 64);
    const int br0 = n0 + srow, br1 = n0 + srow + 64;

    f32x4 acc[4][4];
    const f32x4 z4 = {0.f, 0.f, 0.f, 0.f};
#pragma unroll
    for (int i = 0; i < 4; ++i)
#pragma unroll
        for (int j = 0; j < 4; ++j) acc[i][j] = z4;

    uint4 a0 = load_cvt<AF32>(A, (size_t)ar0 * lda + ch * 8);
    uint4 a1 = load_cvt<AF32>(A, (size_t)ar1 * lda + ch * 8);
    uint4 b0 = load_cvt<BF32>(Bm, (size_t)br0 * ldb + ch * 8);
    uint4 b1 = load_cvt<BF32>(Bm, (size_t)br1 * ldb + ch * 8);

    for (int k0 = 0; k0 < K; k0 += 32) {
        __syncthreads();
        *(uint4*)&As[(srow)      * 32 + ch * 8] = a0;
        *(uint4*)&As[(srow + 64) * 32 + ch * 8] = a1;
        *(uint4*)&Bs[(srow)      * 32 + ch * 8] = b0;
        *(uint4*)&Bs[(srow + 64) * 32 + ch * 8] = b1;
        __syncthreads();
        short8 af[4], bfr[4];
#pragma unroll
        for (int i = 0; i < 4; ++i) af[i]  = *(const short8*)&As[(wm + i * 16 + lr) * 32 + quad * 8];
#pragma unroll
        for (int j = 0; j < 4; ++j) bfr[j] = *(const short8*)&Bs[(wn + j * 16 + lr) * 32 + quad * 8];
        if (k0 + 32 < K) {
            a0 = load_cvt<AF32>(A, (size_t)ar0 * lda + k0 + 32 + ch * 8);
            a1 = load_cvt<AF32>(A, (size_t)ar1 * lda + k0 + 32 + ch * 8);
            b0 = load_cvt<BF32>(Bm, (size_t)br0 * ldb + k0 + 32 + ch * 8);
            b1 = load_cvt<BF32>(Bm, (size_t)br1 * ldb + k0 + 32 + ch * 8);
        }
#pragma unroll
        for (int i = 0; i < 4; ++i)
#pragma unroll
            for (int j = 0; j < 4; ++j) acc[i][j] = mfma16(af[i], bfr[j], acc[i][j]);
    }

#pragma unroll
    for (int i = 0; i < 4; ++i)
#pragma unroll
        for (int r = 0; r < 4; ++r) {
            const int m = m0 + wm + i * 16 + quad * 4 + r;
#pragma unroll
            for (int j = 0; j < 4; ++j) {
                const int n = n0 + wn + j * 16 + lr;
                epi(m, n, acc[i][j][r]);
            }
        }
}

// ---------------------------------------------------------------------------
// Fused prefix: blocks [0,12) compute gi_img = ic_s @ W_ih[:, :2048]^T + b_ih
//               blocks [12,16) compute h0 = ic_s @ init_w^T + init_b -> outs
// Both share the gathered A (image_code, K=2048); fusing overlaps the two
// latency-bound small GEMMs that were previously stream-serialized.
// ---------------------------------------------------------------------------
__global__ __launch_bounds__(256) void k_pfx(
    const float* __restrict__ image_code,
    const int* __restrict__ order,
    const float* __restrict__ W_ih,
    const float* __restrict__ b_ih,
    const float* __restrict__ init_w,
    const float* __restrict__ init_b,
    float* __restrict__ gi_img,
    ushort_t* __restrict__ outs)
{
    __shared__ ushort_t As[128 * 32];
    __shared__ ushort_t Bs[128 * 32];
    const int tid = threadIdx.x;
    const int bx = blockIdx.x;
    const bool isH0 = bx >= 12;
    const float* Bm = isH0 ? init_w : W_ih;
    const int ldb = isH0 ? IC_ : D_;
    const int n0 = isH0 ? (bx - 12) * 128 : bx * 128;
    const float* bias = isH0 ? init_b : b_ih;

    const int w = tid >> 6, lane = tid & 63, quad = lane >> 4, lr = lane & 15;
    const int srow = tid >> 2, ch = tid & 3;
    const int wm = (w & 1) * 64, wn = (w >> 1) * 64;

    const int ar0 = order[srow];
    const int ar1 = order[srow + 64];
    const int br0 = n0 + srow, br1 = n0 + srow + 64;

    f32x4 acc[4][4];
    const f32x4 z4 = {0.f, 0.f, 0.f, 0.f};
#pragma unroll
    for (int i = 0; i < 4; ++i)
#pragma unroll
        for (int j = 0; j < 4; ++j) acc[i][j] = z4;

    uint4 a0 = load_cvt<true>(image_code, (size_t)ar0 * IC_ + ch * 8);
    uint4 a1 = load_cvt<true>(image_code, (size_t)ar1 * IC_ + ch * 8);
    uint4 b0 = load_cvt<true>(Bm, (size_t)br0 * ldb + ch * 8);
    uint4 b1 = load_cvt<true>(Bm, (size_t)br1 * ldb + ch * 8);

    for (int k0 = 0; k0 < IC_; k0 += 32) {
        __syncthreads();
        *(uint4*)&As[(srow)      * 32 + ch * 8] = a0;
        *(uint4*)&As[(srow + 64) * 32 + ch * 8] = a1;
        *(uint4*)&Bs[(srow)      * 32 + ch * 8] = b0;
        *(uint4*)&Bs[(srow + 64) * 32 + ch * 8] = b1;
        __syncthreads();
        short8 af[4], bfr[4];
#pragma unroll
        for (int i = 0; i < 4; ++i) af[i]  = *(const short8*)&As[(wm + i * 16 + lr) * 32 + quad * 8];
#pragma unroll
        for (int j = 0; j < 4; ++j) bfr[j] = *(const short8*)&Bs[(wn + j * 16 + lr) * 32 + quad * 8];
        if (k0 + 32 < IC_) {
            a0 = load_cvt<true>(image_code, (size_t)ar0 * IC_ + k0 + 32 + ch * 8);
            a1 = load_cvt<true>(image_code, (size_t)ar1 * IC_ + k0 + 32 + ch * 8);
            b0 = load_cvt<true>(Bm, (size_t)br0 * ldb + k0 + 32 + ch * 8);
            b1 = load_cvt<true>(Bm, (size_t)br1 * ldb + k0 + 32 + ch * 8);
        }
#pragma unroll
        for (int i = 0; i < 4; ++i)
#pragma unroll
            for (int j = 0; j < 4; ++j) acc[i][j] = mfma16(af[i], bfr[j], acc[i][j]);
    }

#pragma unroll
    for (int i = 0; i < 4; ++i)
#pragma unroll
        for (int r = 0; r < 4; ++r) {
            const int m = wm + i * 16 + quad * 4 + r;
#pragma unroll
            for (int j = 0; j < 4; ++j) {
                const int n = n0 + wn + j * 16 + lr;
                const float v = acc[i][j][r] + bias[n];
                if (isH0) outs[(size_t)m * H_ + n] = f2bf(v);
                else      gi_img[(size_t)m * G3_ + n] = v;
            }
        }
}

// ---------------------------------------------------------------------------
// FUSED recurrence + output projection.
//
// Producers [0,64): g = bid&31, ih = bid>>5. Per step: h A-fragments direct
//   to regs; 48 MFMA; gates (h_old carried in regs); write-through h store;
//   distributed per-producer flags; wave-0-only poll with s_sleep backoff;
//   half leaders publish 8 replicas of the half-ready pair.
// Consumers [64,64+395): nb-AFFINE teams (R4). nb = cid%79 FIXED per block,
//   team = cid/79; block handles t = team, team+5, ... Its 128KB fcw slab
//   stays hot in L2/L3 across its ~6 tiles -> fcw HBM re-fetch (the ~216MB
//   FETCH and the fabric pressure inflating producer round-trips) collapses
//   to ~one pass. K-loop double-buffered like gemm128.
// LDS: producer 48*520 ush = 49,920 B -> 2 blocks/CU; grid 459 <= 512 slots.
// ---------------------------------------------------------------------------
#define PBS_STR 520
__global__ __launch_bounds__(256, 2) void k_fused(
    const ushort_t* __restrict__ whh_bf,   // (32,48,512)
    const ushort_t* __restrict__ gi_full,  // (31*128,1536)
    const float* __restrict__ b_hh,        // (1536)
    ushort_t* __restrict__ outs,           // (32,128,512)
    const ushort_t* __restrict__ fcw_bf,   // (10112,512)
    const float* __restrict__ fc_b,        // (10000)
    const int* __restrict__ len_i,         // (128)
    float* __restrict__ out,               // (128,31,10000)
    int* __restrict__ sync)                // distributed flags (fcw pad rows)
{
    __shared__ __align__(16) ushort_t sm[48 * PBS_STR];
    const int bid = blockIdx.x;
    const int tid = threadIdx.x;
    const int w = tid >> 6, lane = tid & 63, quad = lane >> 4, lr = lane & 15;

    if (bid < NPROD_) {
        // ---------------- producer ----------------
        __builtin_amdgcn_s_setprio(1);     // latency-critical waves win issue arb
        const int g = bid & 31;
        const int ih = bid >> 5;
        const bool leader = (bid == (ih << 5));   // bid 0 and 32
        ushort_t* Bs = sm;                 // 48 x 520

        const ushort_t* wsrc = whh_bf + (size_t)g * 48 * 512;
        for (int i = tid; i < 48 * 64; i += 256) {
            const int row = i >> 6, c = i & 63;
            *(uint4*)&Bs[row * PBS_STR + c * 8] = *(const uint4*)&wsrc[row * 512 + c * 8];
        }
        const int cg = g * 16 + lr;        // gh col
        const float bhn = b_hh[1024 + cg];
        __syncthreads();

        // h_old carried in registers (bf16-rounded); memory load only for h0
        float hold_reg[4];
        {
            const ushort_t* h0p = outs + (size_t)ih * 64 * 512;
#pragma unroll
            for (int r = 0; r < 4; ++r)
                hold_reg[r] = bf2f(h0p[(size_t)(w * 16 + quad * 4 + r) * 512 + cg]);
        }
        // gi prefetch for step 0
        ushort_t gi0[4], gi1[4], gi2[4];
#pragma unroll
        for (int r = 0; r < 4; ++r) {
            const int b = ih * 64 + w * 16 + quad * 4 + r;
            const ushort_t* p = gi_full + (size_t)b * G3_ + cg;
            gi0[r] = p[0]; gi1[r] = p[512]; gi2[r] = p[1024];
        }

        for (int step = 0; step < T_; ++step) {
            const ushort_t* hsrc = outs + (size_t)step * (128 * 512) + (size_t)ih * 64 * 512;

            // h_t A-fragments: per-lane contiguous 16B chunks straight to regs
            uint4 hv[16];
            const ushort_t* hrow = hsrc + (size_t)(w * 16 + lr) * 512 + quad * 8;
#pragma unroll
            for (int kk = 0; kk < 16; ++kk)
                hv[kk] = *(const uint4*)(hrow + kk * 32);

            f32x4 acc[3];
#pragma unroll
            for (int j = 0; j < 3; ++j) acc[j] = (f32x4){0.f, 0.f, 0.f, 0.f};
#pragma unroll
            for (int kk = 0; kk < 16; ++kk) {
                union { uint4 v; short8 s; } cc; cc.v = hv[kk];
                const short8 af = cc.s;
#pragma unroll
                for (int j = 0; j < 3; ++j) {
                    const short8 bf = *(const short8*)&Bs[(j * 16 + lr) * PBS_STR + kk * 32 + quad * 8];
                    acc[j] = mfma16(af, bf, acc[j]);
                }
            }

            // gates (C-layout: col=lr, row=quad*4+r)
            ushort_t* hdst = outs + (size_t)(step + 1) * (128 * 512);
#pragma unroll
            for (int r = 0; r < 4; ++r) {
                const int b = ih * 64 + w * 16 + quad * 4 + r;
                const float ir  = bf2f(gi0[r]);
                const float iz  = bf2f(gi1[r]);
                const float in_ = bf2f(gi2[r]);
                const float hr = acc[0][r];
                const float hz = acc[1][r];
                const float hn = acc[2][r] + bhn;
                const float rg = 1.f / (1.f + __expf(-(ir + hr)));
                const float zg = 1.f / (1.f + __expf(-(iz + hz)));
                const float nn = tanhf(in_ + rg * hn);
                const float hnew = (1.f - zg) * nn + zg * hold_reg[r];
                const unsigned int hb = (unsigned int)f2bf(hnew);
                hold_reg[r] = bf2f((unsigned short)hb);   // bit-compat carry
                const unsigned int pv = (unsigned int)__shfl_xor((int)hb, 1);
                if ((lr & 1) == 0) {
                    const unsigned int word = hb | (pv << 16);
                    __hip_atomic_store((unsigned int*)&hdst[(size_t)b * 512 + cg], word,
                                       __ATOMIC_RELAXED, __HIP_MEMORY_SCOPE_AGENT);
                }
            }

            // release: drain write-through stores, then distributed signal
            asm volatile("s_waitcnt vmcnt(0)" ::: "memory");
            __syncthreads();          // all 4 waves' stores are at coherence point
            const int tgt = step + 1;
            if (tid == 0)
                __hip_atomic_store(&sync[bid * 8], tgt,
                                   __ATOMIC_RELAXED, __HIP_MEMORY_SCOPE_AGENT);

            // prefetch next step's gi (independent of h) under the wait
            ushort_t ng0[4], ng1[4], ng2[4];
            if (step + 1 < T_) {
                const size_t gb = (size_t)(step + 1) * 128 * G3_;
#pragma unroll
                for (int r = 0; r < 4; ++r) {
                    const int b = ih * 64 + w * 16 + quad * 4 + r;
                    const ushort_t* p = gi_full + gb + (size_t)b * G3_ + cg;
                    ng0[r] = p[0]; ng1[r] = p[512]; ng2[r] = p[1024];
                }
            }
            asm volatile("" ::: "memory");

            // wave 0 only polls the 32 same-half flags, with backoff
            if (w == 0 && (step < T_ - 1 || leader)) {
                const int* pf = &sync[(ih * 32 + (lane & 31)) * 8];
                for (;;) {
                    const int v = __hip_atomic_load(pf, __ATOMIC_RELAXED, __HIP_MEMORY_SCOPE_AGENT);
                    if (__all(v >= tgt)) break;
                    __builtin_amdgcn_s_sleep(1);
                }
                if (leader && lane == 0) {
#pragma unroll
                    for (int k = 0; k < 8; ++k)
                        __hip_atomic_store(&sync[768 + k * 16 + ih], tgt,
                                           __ATOMIC_RELAXED, __HIP_MEMORY_SCOPE_AGENT);
                }
            }
            __syncthreads();          // release waves 1-3
            asm volatile("" ::: "memory");

            if (step + 1 < T_) {
#pragma unroll
                for (int r = 0; r < 4; ++r) { gi0[r] = ng0[r]; gi1[r] = ng1[r]; gi2[r] = ng2[r]; }
            }
        }
    } else {
        // ---------------- nb-affine consumer (preds tiles) ----------------
        const int cid = bid - NPROD_;          // [0, 395)
        const int nb = cid % 79;               // FIXED fcw slab per block
        const int team = cid / 79;             // [0, 5)
        const int n0 = nb * 128;
        ushort_t* As = sm;            // 128 x 32
        ushort_t* Bs = sm + 4096;     // 128 x 32
        const int srow = tid >> 2, ch = tid & 3;
        const int wm = (w & 1) * 64, wn = (w >> 1) * 64;
        const ull_t* hready = (const ull_t*)&sync[768 + (cid & 7) * 16];

        // hoisted per-block epilogue constants
        float fcb[4];
#pragma unroll
        for (int j = 0; j < 4; ++j) {
            const int n = n0 + wn + j * 16 + lr;
            fcb[j] = (n < V_) ? fc_b[n] : 0.f;
        }

        for (int t = team; t < T_; t += NTEAM_) {
            if (tid == 0) {
                for (;;) {
                    const ull_t hv8 = __hip_atomic_load(hready, __ATOMIC_RELAXED, __HIP_MEMORY_SCOPE_AGENT);
                    const int l0 = (int)(unsigned int)(hv8 & 0xffffffffull);
                    const int l1 = (int)(unsigned int)(hv8 >> 32);
                    if (l0 > t && l1 > t) break;
                    __builtin_amdgcn_s_sleep(16);
                }
            }
            __syncthreads();

            const ushort_t* A = outs + (size_t)(t + 1) * (128 * 512);

            f32x4 acc[4][4];
            const f32x4 z4 = {0.f, 0.f, 0.f, 0.f};
#pragma unroll
            for (int i = 0; i < 4; ++i)
#pragma unroll
                for (int j = 0; j < 4; ++j) acc[i][j] = z4;

            uint4 a0 = *(const uint4*)&A[(size_t)srow * 512 + ch * 8];
            uint4 a1 = *(const uint4*)&A[(size_t)(srow + 64) * 512 + ch * 8];
            uint4 b0 = *(const uint4*)&fcw_bf[(size_t)(n0 + srow)      * 512 + ch * 8];
            uint4 b1 = *(const uint4*)&fcw_bf[(size_t)(n0 + srow + 64) * 512 + ch * 8];

            for (int k0 = 0; k0 < 512; k0 += 32) {
                __syncthreads();
                *(uint4*)&As[(srow)      * 32 + ch * 8] = a0;
                *(uint4*)&As[(srow + 64) * 32 + ch * 8] = a1;
                *(uint4*)&Bs[(srow)      * 32 + ch * 8] = b0;
                *(uint4*)&Bs[(srow + 64) * 32 + ch * 8] = b1;
                __syncthreads();
                short8 af[4], bfr[4];
#pragma unroll
                for (int i = 0; i < 4; ++i) af[i]  = *(const short8*)&As[(wm + i * 16 + lr) * 32 + quad * 8];
#pragma unroll
                for (int j = 0; j < 4; ++j) bfr[j] = *(const short8*)&Bs[(wn + j * 16 + lr) * 32 + quad * 8];
                if (k0 + 32 < 512) {
                    a0 = *(const uint4*)&A[(size_t)srow * 512 + k0 + 32 + ch * 8];
                    a1 = *(const uint4*)&A[(size_t)(srow + 64) * 512 + k0 + 32 + ch * 8];
                    b0 = *(const uint4*)&fcw_bf[(size_t)(n0 + srow)      * 512 + k0 + 32 + ch * 8];
                    b1 = *(const uint4*)&fcw_bf[(size_t)(n0 + srow + 64) * 512 + k0 + 32 + ch * 8];
                }
#pragma unroll
                for (int i = 0; i < 4; ++i)
#pragma unroll
                    for (int j = 0; j < 4; ++j) acc[i][j] = mfma16(af[i], bfr[j], acc[i][j]);
            }

#pragma unroll
            for (int i = 0; i < 4; ++i)
#pragma unroll
                for (int r = 0; r < 4; ++r) {
                    const int b = wm + i * 16 + quad * 4 + r;
                    const bool act = (t < len_i[b]);
                    const size_t base = (size_t)b * T_ * V_ + (size_t)t * V_;
#pragma unroll
                    for (int j = 0; j < 4; ++j) {
                        const int n = n0 + wn + j * 16 + lr;
                        if (n < V_) out[base + n] = act ? (acc[i][j][r] + fcb[j]) : 0.f;
                    }
                }
        }
    }
}

// ---------------------------------------------------------------------------
extern "C" void kernel_launch(void* const* d_in, const int* in_sizes, int n_in,
                              void* d_out, int out_size, void* d_ws, size_t ws_size,
                              hipStream_t stream) {
    const float* image_code = (const float*)d_in[0];
    const int*   captions   = (const int*)d_in[1];
    const int*   cap_lens   = (const int*)d_in[2];
    const float* embed_w    = (const float*)d_in[3];
    const float* W_ih       = (const float*)d_in[4];
    const float* W_hh       = (const float*)d_in[5];
    const float* b_ih       = (const float*)d_in[6];
    const float* b_hh       = (const float*)d_in[7];
    const float* fc_w       = (const float*)d_in[8];
    const float* fc_b       = (const float*)d_in[9];
    const float* init_w     = (const float*)d_in[10];
    const float* init_b     = (const float*)d_in[11];

    float* out = (float*)d_out;
    char* ws = (char*)d_ws;
    int*      order   = (int*)(ws + WS_ORDER);
    int*      len_i   = (int*)(ws + WS_LEN);
    int*      tok     = (int*)(ws + WS_TOK);
    int*      bar     = (int*)(ws + WS_BAR);
    float*    gi_img  = (float*)(ws + WS_GIIMG);
    ushort_t* whh_bf  = (ushort_t*)(ws + WS_WHH);
    ushort_t* gi_full = (ushort_t*)(ws + WS_GIFULL);
    ushort_t* outs_bf = (ushort_t*)(ws + WS_OUTS);
    ushort_t* fcw_bf  = (ushort_t*)(ws + WS_FCW);
    // distributed sync flags overlay the zero-padded fcw rows [10108,10112)
    int*      sync    = (int*)(fcw_bf + ((size_t)NPAD_ - 4) * 512);

    // 1) sort + token table + int-ish outputs
    hipLaunchKernelGGL(k_prep, dim3(1), dim3(128), 0, stream,
                       captions, cap_lens, order, len_i, tok, bar,
                       out + (size_t)B_ * T_ * V_);

    // 2) weight conversions (k_cvt_fcw also zeroes the flag region each iter)
    hipLaunchKernelGGL(k_cvt_fcw, dim3((NPAD_ * 64) / 256), dim3(256), 0, stream,
                       fc_w, fcw_bf);
    hipLaunchKernelGGL(k_cvt_whh, dim3((G3_ * H_ / 8) / 256), dim3(256), 0, stream,
                       W_hh, whh_bf);

    // 3+4) fused prefix: gi_img (12 blocks) + h0 (4 blocks), overlapped
    hipLaunchKernelGGL(k_pfx, dim3(16), dim3(256), 0, stream,
                       image_code, order, W_ih, b_ih, init_w, init_b,
                       gi_img, outs_bf);

    // 5) gi_full = emb @ W_ih[:, 2048:]^T + gi_img[b] + b_hh(r,z)
    hipLaunchKernelGGL((gemm128<true, true, EpiAdd2D>), dim3(12, 31), dim3(256), 0, stream,
                       embed_w, WD_, tok, W_ih + IC_, D_, WD_,
                       EpiAdd2D{gi_full, G3_, gi_img, G3_, b_hh});

    // 6) fused persistent recurrence + streaming output projection
    hipLaunchKernelGGL(k_fused, dim3(NPROD_ + NCONS_), dim3(256), 0, stream,
                       whh_bf, gi_full, b_hh, outs_bf,
                       fcw_bf, fc_b, len_i, out, sync);
}

// Round 5
// 498.200 us; speedup vs baseline: 1.9268x; 1.0800x over previous
//
#include <hip/hip_runtime.h>
#include <math.h>

#define B_   128
#define L_   32
#define T_   31
#define V_   10000
#define IC_  2048
#define WD_  512
#define H_   512
#define D_   2560
#define G3_  1536   // 3*H
#define NPAD_ 10112 // V padded to 79*128
#define NPROD_ 64                 // producer blocks (solo CUs)
#define NCONS_ 158                // consumers = 79 nb-slots x 2 teams
#define NTEAM_ 2
// k_setup block-role layout (low bids start first -> latency-critical first)
#define SU_PFX0 1
#define SU_FCW0 17
#define SU_WHH0 (SU_FCW0 + 2528)
#define SU_N    (SU_WHH0 + 384)

typedef short short8 __attribute__((ext_vector_type(8)));
typedef float f32x4  __attribute__((ext_vector_type(4)));
typedef unsigned short ushort_t;
typedef unsigned long long ull_t;

__device__ __forceinline__ unsigned short f2bf(float f) {
    unsigned int u = __builtin_bit_cast(unsigned int, f);
    unsigned int r = (u + 0x7FFFu + ((u >> 16) & 1u)) >> 16;
    return (unsigned short)r;
}
__device__ __forceinline__ float bf2f(unsigned short h) {
    unsigned int u = ((unsigned int)h) << 16;
    return __builtin_bit_cast(float, u);
}
__device__ __forceinline__ f32x4 mfma16(short8 a, short8 b, f32x4 c) {
    return __builtin_amdgcn_mfma_f32_16x16x32_bf16(a, b, c, 0, 0, 0);
}

// ---- workspace layout (byte offsets) ----
#define WS_ORDER  0          // int[128]
#define WS_LEN    512        // int[128]
#define WS_TOK    1024       // int[3968] -> ends 16896
#define WS_BAR    16896      // int (legacy, zeroed)
#define WS_GIIMG  16960      // float[128*1536]          -> ends 803392
#define WS_WHH    803392     // bf16 [32][48][512] perm  -> ends 2376256
#define WS_GIFULL 2376256    // bf16 [3968*1536]         -> ends 14565952
#define WS_OUTS   14565952   // bf16 [32*128*512]        -> ends 18760256
#define WS_FCW    18760256   // bf16 [10112*512]         -> ends 29114944
// sync flags live inside the zero-padded fcw rows [10108,10112) (4096 B):
//   - zeroed every iteration by the cvt_fcw role (rows >= V_ write 0)
//   - read as B-operand only for output cols n >= V_, which are masked
//   int sync[i*8]          : per-producer flag i in [0,64), value = step+1
//   int sync[768 + k*16+ih]: half-ready replica k in [0,8) (8B-pair loadable)

// ---------------------------------------------------------------------------
template<bool F32>
__device__ __forceinline__ uint4 load_cvt(const void* src, size_t off) {
    if constexpr (!F32) {
        return *(const uint4*)((const unsigned short*)src + off);
    } else {
        const float* p = (const float*)src + off;
        const float4 x = *(const float4*)p;
        const float4 y = *(const float4*)(p + 4);
        union { unsigned short u[8]; uint4 v; } r;
        r.u[0]=f2bf(x.x); r.u[1]=f2bf(x.y); r.u[2]=f2bf(x.z); r.u[3]=f2bf(x.w);
        r.u[4]=f2bf(y.x); r.u[5]=f2bf(y.y); r.u[6]=f2bf(y.z); r.u[7]=f2bf(y.w);
        return r.v;
    }
}

// ---------------------------------------------------------------------------
// k_setup: ONE launch for all preprocessing.
//   bid 0            : prep (sort, tok table, len_i, out tail)
//   bid [1,17)       : pfx  (gi_img 12 blocks + h0 4 blocks; order recomputed
//                      IN-BLOCK from cap_lens -> no intra-kernel dependency)
//   bid [17,2545)    : fc_w -> bf16 (pads rows >= V_ with 0, zeroes sync)
//   bid [2545,2929)  : W_hh -> bf16 permuted 32x48x512
// ---------------------------------------------------------------------------
__global__ __launch_bounds__(256) void k_setup(
    const int* __restrict__ captions,
    const int* __restrict__ cap_lens,
    const float* __restrict__ fc_w,
    const float* __restrict__ W_hh,
    const float* __restrict__ image_code,
    const float* __restrict__ W_ih,
    const float* __restrict__ b_ih,
    const float* __restrict__ init_w,
    const float* __restrict__ init_b,
    ushort_t* __restrict__ fcw_bf,
    ushort_t* __restrict__ whh_bf,
    float* __restrict__ gi_img,
    ushort_t* __restrict__ outs,
    int* __restrict__ order,
    int* __restrict__ len_i,
    int* __restrict__ tok,
    int* __restrict__ bar,
    float* __restrict__ out_tail)
{
    __shared__ __align__(16) ushort_t As[128 * 32];
    __shared__ __align__(16) ushort_t Bs[128 * 32];
    __shared__ int s_len[B_];
    __shared__ int s_ord[B_];
    const int bid = blockIdx.x;
    const int tid = threadIdx.x;

    if (bid >= SU_FCW0 && bid < SU_WHH0) {
        // ---- fc_w convert (bulk of the grid) ----
        const int idx = (bid - SU_FCW0) * 256 + tid;
        const int row = idx >> 6;
        const int ch  = idx & 63;
        union { unsigned short u[8]; uint4 v; } r;
        if (row < V_) {
            const float* p = fc_w + (size_t)row * 512 + ch * 8;
            const float4 x = *(const float4*)p;
            const float4 y = *(const float4*)(p + 4);
            r.u[0]=f2bf(x.x); r.u[1]=f2bf(x.y); r.u[2]=f2bf(x.z); r.u[3]=f2bf(x.w);
            r.u[4]=f2bf(y.x); r.u[5]=f2bf(y.y); r.u[6]=f2bf(y.z); r.u[7]=f2bf(y.w);
        } else {
            r.v = make_uint4(0, 0, 0, 0);
        }
        *(uint4*)&fcw_bf[(size_t)row * 512 + ch * 8] = r.v;
        return;
    }
    if (bid >= SU_WHH0) {
        // ---- W_hh convert/permute ----
        const int idx = (bid - SU_WHH0) * 256 + tid;
        const size_t o = (size_t)idx * 8;
        const int g = (int)(o / (48 * 512));
        const int rem = (int)(o % (48 * 512));
        const int j = rem >> 9;
        const int k = rem & 511;
        const int srow = (j >> 4) * 512 + g * 16 + (j & 15);
        const float* p = W_hh + (size_t)srow * 512 + k;
        const float4 x = *(const float4*)p;
        const float4 y = *(const float4*)(p + 4);
        union { unsigned short u[8]; uint4 v; } r;
        r.u[0]=f2bf(x.x); r.u[1]=f2bf(x.y); r.u[2]=f2bf(x.z); r.u[3]=f2bf(x.w);
        r.u[4]=f2bf(y.x); r.u[5]=f2bf(y.y); r.u[6]=f2bf(y.z); r.u[7]=f2bf(y.w);
        *(uint4*)&whh_bf[o] = r.v;
        return;
    }

    // prep + pfx both need the sorted order: recompute locally (O(128^2), ~µs)
    if (tid < B_) s_len[tid] = cap_lens[tid];
    __syncthreads();
    if (tid < B_) {
        const int myl = s_len[tid];
        int rank = 0;
        for (int k = 0; k < B_; ++k) {
            const int lk = s_len[k];
            if (lk > myl || (lk == myl && k < tid)) rank++;
        }
        s_ord[rank] = tid;
    }
    __syncthreads();

    if (bid == 0) {
        // ---- prep ----
        if (tid == 0) *bar = 0;
        if (tid < B_) {
            const int o = s_ord[tid];
            order[tid] = o;
            const int ln = s_len[o] - 1;
            len_i[tid] = ln;
            out_tail[B_ * L_ + tid]      = (float)ln;
            out_tail[B_ * L_ + B_ + tid] = (float)o;
        }
        __syncthreads();
        for (int i = tid; i < B_ * L_; i += 256) {
            const int b = i / L_, l = i % L_;
            const int c = captions[s_ord[b] * L_ + l];
            out_tail[i] = (float)c;
            if (l < T_) tok[l * B_ + b] = c;
        }
        return;
    }

    // ---- pfx: gi_img (bids 1..12) / h0 (bids 13..16) ----
    const int px = bid - SU_PFX0;           // [0,16)
    const bool isH0 = px >= 12;
    const float* Bm = isH0 ? init_w : W_ih;
    const int ldb = isH0 ? IC_ : D_;
    const int n0 = isH0 ? (px - 12) * 128 : px * 128;
    const float* bias = isH0 ? init_b : b_ih;

    const int w = tid >> 6, lane = tid & 63, quad = lane >> 4, lr = lane & 15;
    const int srow = tid >> 2, ch = tid & 3;
    const int wm = (w & 1) * 64, wn = (w >> 1) * 64;

    const int ar0 = s_ord[srow];
    const int ar1 = s_ord[srow + 64];
    const int br0 = n0 + srow, br1 = n0 + srow + 64;

    f32x4 acc[4][4];
    const f32x4 z4 = {0.f, 0.f, 0.f, 0.f};
#pragma unroll
    for (int i = 0; i < 4; ++i)
#pragma unroll
        for (int j = 0; j < 4; ++j) acc[i][j] = z4;

    uint4 a0 = load_cvt<true>(image_code, (size_t)ar0 * IC_ + ch * 8);
    uint4 a1 = load_cvt<true>(image_code, (size_t)ar1 * IC_ + ch * 8);
    uint4 b0 = load_cvt<true>(Bm, (size_t)br0 * ldb + ch * 8);
    uint4 b1 = load_cvt<true>(Bm, (size_t)br1 * ldb + ch * 8);

    for (int k0 = 0; k0 < IC_; k0 += 32) {
        __syncthreads();
        *(uint4*)&As[(srow)      * 32 + ch * 8] = a0;
        *(uint4*)&As[(srow + 64) * 32 + ch * 8] = a1;
        *(uint4*)&Bs[(srow)      * 32 + ch * 8] = b0;
        *(uint4*)&Bs[(srow + 64) * 32 + ch * 8] = b1;
        __syncthreads();
        short8 af[4], bfr[4];
#pragma unroll
        for (int i = 0; i < 4; ++i) af[i]  = *(const short8*)&As[(wm + i * 16 + lr) * 32 + quad * 8];
#pragma unroll
        for (int j = 0; j < 4; ++j) bfr[j] = *(const short8*)&Bs[(wn + j * 16 + lr) * 32 + quad * 8];
        if (k0 + 32 < IC_) {
            a0 = load_cvt<true>(image_code, (size_t)ar0 * IC_ + k0 + 32 + ch * 8);
            a1 = load_cvt<true>(image_code, (size_t)ar1 * IC_ + k0 + 32 + ch * 8);
            b0 = load_cvt<true>(Bm, (size_t)br0 * ldb + k0 + 32 + ch * 8);
            b1 = load_cvt<true>(Bm, (size_t)br1 * ldb + k0 + 32 + ch * 8);
        }
#pragma unroll
        for (int i = 0; i < 4; ++i)
#pragma unroll
            for (int j = 0; j < 4; ++j) acc[i][j] = mfma16(af[i], bfr[j], acc[i][j]);
    }

#pragma unroll
    for (int i = 0; i < 4; ++i)
#pragma unroll
        for (int r = 0; r < 4; ++r) {
            const int m = wm + i * 16 + quad * 4 + r;
#pragma unroll
            for (int j = 0; j < 4; ++j) {
                const int n = n0 + wn + j * 16 + lr;
                const float v = acc[i][j][r] + bias[n];
                if (isH0) outs[(size_t)m * H_ + n] = f2bf(v);
                else      gi_img[(size_t)m * G3_ + n] = v;
            }
        }
}

struct EpiAdd2D {                 // gi_full = giw + gi_img[b] (+ b_hh for r,z)
    ushort_t* C; int ldc; const float* add; int addld; const float* bhh;
    __device__ void operator()(int m, int n, float v) const {
        const float extra = (n < 1024) ? bhh[n] : 0.f;
        C[(size_t)m * ldc + n] = f2bf(v + add[(size_t)(m & 127) * addld + n] + extra);
    }
};

// ---------------------------------------------------------------------------
// NT GEMM, 128x128 tile, BK=32, double-buffered (gi_full only now).
// ---------------------------------------------------------------------------
template<bool AF32, bool BF32, class Epi>
__global__ __launch_bounds__(256) void gemm128(
    const void* __restrict__ A, int lda, const int* __restrict__ gidx,
    const void* __restrict__ Bm, int ldb, int K, Epi epi)
{
    __shared__ ushort_t As[128 * 32];
    __shared__ ushort_t Bs[128 * 32];
    const int tid = threadIdx.x;
    const int m0 = blockIdx.y * 128, n0 = blockIdx.x * 128;
    const int w = tid >> 6, lane = tid & 63, quad = lane >> 4, lr = lane & 15;
    const int srow = tid >> 2, ch = tid & 3;
    const int wm = (w & 1) * 64, wn = (w >> 1) * 64;

    const int ar0 = gidx ? gidx[m0 + srow]      : (m0 + srow);
    const int ar1 = gidx ? gidx[m0 + srow + 64] : (m0 + srow + 64);
    const int br0 = n0 + srow, br1 = n0 + srow + 64;

    f32x4 acc[4][4];
    const f32x4 z4 = {0.f, 0.f, 0.f, 0.f};
#pragma unroll
    for (int i = 0; i < 4; ++i)
#pragma unroll
        for (int j = 0; j < 4; ++j) acc[i][j] = z4;

    uint4 a0 = load_cvt<AF32>(A, (size_t)ar0 * lda + ch * 8);
    uint4 a1 = load_cvt<AF32>(A, (size_t)ar1 * lda + ch * 8);
    uint4 b0 = load_cvt<BF32>(Bm, (size_t)br0 * ldb + ch * 8);
    uint4 b1 = load_cvt<BF32>(Bm, (size_t)br1 * ldb + ch * 8);

    for (int k0 = 0; k0 < K; k0 += 32) {
        __syncthreads();
        *(uint4*)&As[(srow)      * 32 + ch * 8] = a0;
        *(uint4*)&As[(srow + 64) * 32 + ch * 8] = a1;
        *(uint4*)&Bs[(srow)      * 32 + ch * 8] = b0;
        *(uint4*)&Bs[(srow + 64) * 32 + ch * 8] = b1;
        __syncthreads();
        short8 af[4], bfr[4];
#pragma unroll
        for (int i = 0; i < 4; ++i) af[i]  = *(const short8*)&As[(wm + i * 16 + lr) * 32 + quad * 8];
#pragma unroll
        for (int j = 0; j < 4; ++j) bfr[j] = *(const short8*)&Bs[(wn + j * 16 + lr) * 32 + quad * 8];
        if (k0 + 32 < K) {
            a0 = load_cvt<AF32>(A, (size_t)ar0 * lda + k0 + 32 + ch * 8);
            a1 = load_cvt<AF32>(A, (size_t)ar1 * lda + k0 + 32 + ch * 8);
            b0 = load_cvt<BF32>(Bm, (size_t)br0 * ldb + k0 + 32 + ch * 8);
            b1 = load_cvt<BF32>(Bm, (size_t)br1 * ldb + k0 + 32 + ch * 8);
        }
#pragma unroll
        for (int i = 0; i < 4; ++i)
#pragma unroll
            for (int j = 0; j < 4; ++j) acc[i][j] = mfma16(af[i], bfr[j], acc[i][j]);
    }

#pragma unroll
    for (int i = 0; i < 4; ++i)
#pragma unroll
        for (int r = 0; r < 4; ++r) {
            const int m = m0 + wm + i * 16 + quad * 4 + r;
#pragma unroll
            for (int j = 0; j < 4; ++j) {
                const int n = n0 + wn + j * 16 + lr;
                epi(m, n, acc[i][j][r]);
            }
        }
}

// ---------------------------------------------------------------------------
// FUSED recurrence + output projection — SOLO-CU edition (R5).
// 84 KB static LDS -> hardware-enforced 1 block/CU; grid 222 <= 256 CUs ->
// all blocks resident with NO dispatch-order assumption. Producers no longer
// share CUs with consumer GEMM blocks (the theory: pipe-occupancy
// interference, not sync latency, was the 6.5us/step cadence).
// Producers [0,64): unchanged structure (flags, wave-0 poll, reg-carried h).
// Consumers [64,222): nb = cid%79 FIXED, team = cid/79 in {0,1}; t = team,
// team+2, ... -> ~20 consumer blocks/XCD x 128KB slab = 2.5MB < 4MB L2 ->
// fcw slabs finally L2-resident.
// ---------------------------------------------------------------------------
#define PBS_STR 520
__global__ __launch_bounds__(256, 1) void k_fused(
    const ushort_t* __restrict__ whh_bf,   // (32,48,512)
    const ushort_t* __restrict__ gi_full,  // (31*128,1536)
    const float* __restrict__ b_hh,        // (1536)
    ushort_t* __restrict__ outs,           // (32,128,512)
    const ushort_t* __restrict__ fcw_bf,   // (10112,512)
    const float* __restrict__ fc_b,        // (10000)
    const int* __restrict__ len_i,         // (128)
    float* __restrict__ out,               // (128,31,10000)
    int* __restrict__ sync)                // distributed flags (fcw pad rows)
{
    __shared__ __align__(16) ushort_t sm[43008];   // 86,016 B -> 1 block/CU
    const int bid = blockIdx.x;
    const int tid = threadIdx.x;
    const int w = tid >> 6, lane = tid & 63, quad = lane >> 4, lr = lane & 15;

    if (bid < NPROD_) {
        // ---------------- producer (solo CU) ----------------
        __builtin_amdgcn_s_setprio(1);
        const int g = bid & 31;
        const int ih = bid >> 5;
        const bool leader = (bid == (ih << 5));   // bid 0 and 32
        ushort_t* Bs = sm;                 // 48 x 520

        const ushort_t* wsrc = whh_bf + (size_t)g * 48 * 512;
        for (int i = tid; i < 48 * 64; i += 256) {
            const int row = i >> 6, c = i & 63;
            *(uint4*)&Bs[row * PBS_STR + c * 8] = *(const uint4*)&wsrc[row * 512 + c * 8];
        }
        const int cg = g * 16 + lr;        // gh col
        const float bhn = b_hh[1024 + cg];
        __syncthreads();

        // h_old carried in registers (bf16-rounded); memory load only for h0
        float hold_reg[4];
        {
            const ushort_t* h0p = outs + (size_t)ih * 64 * 512;
#pragma unroll
            for (int r = 0; r < 4; ++r)
                hold_reg[r] = bf2f(h0p[(size_t)(w * 16 + quad * 4 + r) * 512 + cg]);
        }
        // gi prefetch for step 0
        ushort_t gi0[4], gi1[4], gi2[4];
#pragma unroll
        for (int r = 0; r < 4; ++r) {
            const int b = ih * 64 + w * 16 + quad * 4 + r;
            const ushort_t* p = gi_full + (size_t)b * G3_ + cg;
            gi0[r] = p[0]; gi1[r] = p[512]; gi2[r] = p[1024];
        }

        for (int step = 0; step < T_; ++step) {
            const ushort_t* hsrc = outs + (size_t)step * (128 * 512) + (size_t)ih * 64 * 512;

            // h_t A-fragments: per-lane contiguous 16B chunks straight to regs
            uint4 hv[16];
            const ushort_t* hrow = hsrc + (size_t)(w * 16 + lr) * 512 + quad * 8;
#pragma unroll
            for (int kk = 0; kk < 16; ++kk)
                hv[kk] = *(const uint4*)(hrow + kk * 32);

            f32x4 acc[3];
#pragma unroll
            for (int j = 0; j < 3; ++j) acc[j] = (f32x4){0.f, 0.f, 0.f, 0.f};
#pragma unroll
            for (int kk = 0; kk < 16; ++kk) {
                union { uint4 v; short8 s; } cc; cc.v = hv[kk];
                const short8 af = cc.s;
#pragma unroll
                for (int j = 0; j < 3; ++j) {
                    const short8 bf = *(const short8*)&Bs[(j * 16 + lr) * PBS_STR + kk * 32 + quad * 8];
                    acc[j] = mfma16(af, bf, acc[j]);
                }
            }

            // gates (C-layout: col=lr, row=quad*4+r)
            ushort_t* hdst = outs + (size_t)(step + 1) * (128 * 512);
#pragma unroll
            for (int r = 0; r < 4; ++r) {
                const int b = ih * 64 + w * 16 + quad * 4 + r;
                const float ir  = bf2f(gi0[r]);
                const float iz  = bf2f(gi1[r]);
                const float in_ = bf2f(gi2[r]);
                const float hr = acc[0][r];
                const float hz = acc[1][r];
                const float hn = acc[2][r] + bhn;
                const float rg = 1.f / (1.f + __expf(-(ir + hr)));
                const float zg = 1.f / (1.f + __expf(-(iz + hz)));
                const float nn = tanhf(in_ + rg * hn);
                const float hnew = (1.f - zg) * nn + zg * hold_reg[r];
                const unsigned int hb = (unsigned int)f2bf(hnew);
                hold_reg[r] = bf2f((unsigned short)hb);   // bit-compat carry
                const unsigned int pv = (unsigned int)__shfl_xor((int)hb, 1);
                if ((lr & 1) == 0) {
                    const unsigned int word = hb | (pv << 16);
                    __hip_atomic_store((unsigned int*)&hdst[(size_t)b * 512 + cg], word,
                                       __ATOMIC_RELAXED, __HIP_MEMORY_SCOPE_AGENT);
                }
            }

            // release: drain write-through stores, then distributed signal
            asm volatile("s_waitcnt vmcnt(0)" ::: "memory");
            __syncthreads();
            const int tgt = step + 1;
            if (tid == 0)
                __hip_atomic_store(&sync[bid * 8], tgt,
                                   __ATOMIC_RELAXED, __HIP_MEMORY_SCOPE_AGENT);

            // prefetch next step's gi (independent of h) under the wait
            ushort_t ng0[4], ng1[4], ng2[4];
            if (step + 1 < T_) {
                const size_t gb = (size_t)(step + 1) * 128 * G3_;
#pragma unroll
                for (int r = 0; r < 4; ++r) {
                    const int b = ih * 64 + w * 16 + quad * 4 + r;
                    const ushort_t* p = gi_full + gb + (size_t)b * G3_ + cg;
                    ng0[r] = p[0]; ng1[r] = p[512]; ng2[r] = p[1024];
                }
            }
            asm volatile("" ::: "memory");

            // wave 0 only polls the 32 same-half flags, with backoff
            if (w == 0 && (step < T_ - 1 || leader)) {
                const int* pf = &sync[(ih * 32 + (lane & 31)) * 8];
                for (;;) {
                    const int v = __hip_atomic_load(pf, __ATOMIC_RELAXED, __HIP_MEMORY_SCOPE_AGENT);
                    if (__all(v >= tgt)) break;
                    __builtin_amdgcn_s_sleep(1);
                }
                if (leader && lane == 0) {
#pragma unroll
                    for (int k = 0; k < 8; ++k)
                        __hip_atomic_store(&sync[768 + k * 16 + ih], tgt,
                                           __ATOMIC_RELAXED, __HIP_MEMORY_SCOPE_AGENT);
                }
            }
            __syncthreads();          // release waves 1-3
            asm volatile("" ::: "memory");

            if (step + 1 < T_) {
#pragma unroll
                for (int r = 0; r < 4; ++r) { gi0[r] = ng0[r]; gi1[r] = ng1[r]; gi2[r] = ng2[r]; }
            }
        }
    } else {
        // ---------------- nb-affine consumer (solo CU) ----------------
        const int cid = bid - NPROD_;          // [0, 158)
        const int nb = cid % 79;               // FIXED fcw slab per block
        const int team = cid / 79;             // {0, 1}
        const int n0 = nb * 128;
        ushort_t* As = sm;            // 128 x 32
        ushort_t* Bs = sm + 4096;     // 128 x 32
        const int srow = tid >> 2, ch = tid & 3;
        const int wm = (w & 1) * 64, wn = (w >> 1) * 64;
        const ull_t* hready = (const ull_t*)&sync[768 + (cid & 7) * 16];

        float fcb[4];
#pragma unroll
        for (int j = 0; j < 4; ++j) {
            const int n = n0 + wn + j * 16 + lr;
            fcb[j] = (n < V_) ? fc_b[n] : 0.f;
        }

        for (int t = team; t < T_; t += NTEAM_) {
            if (tid == 0) {
                for (;;) {
                    const ull_t hv8 = __hip_atomic_load(hready, __ATOMIC_RELAXED, __HIP_MEMORY_SCOPE_AGENT);
                    const int l0 = (int)(unsigned int)(hv8 & 0xffffffffull);
                    const int l1 = (int)(unsigned int)(hv8 >> 32);
                    if (l0 > t && l1 > t) break;
                    __builtin_amdgcn_s_sleep(16);
                }
            }
            __syncthreads();

            const ushort_t* A = outs + (size_t)(t + 1) * (128 * 512);

            f32x4 acc[4][4];
            const f32x4 z4 = {0.f, 0.f, 0.f, 0.f};
#pragma unroll
            for (int i = 0; i < 4; ++i)
#pragma unroll
                for (int j = 0; j < 4; ++j) acc[i][j] = z4;

            uint4 a0 = *(const uint4*)&A[(size_t)srow * 512 + ch * 8];
            uint4 a1 = *(const uint4*)&A[(size_t)(srow + 64) * 512 + ch * 8];
            uint4 b0 = *(const uint4*)&fcw_bf[(size_t)(n0 + srow)      * 512 + ch * 8];
            uint4 b1 = *(const uint4*)&fcw_bf[(size_t)(n0 + srow + 64) * 512 + ch * 8];

            for (int k0 = 0; k0 < 512; k0 += 32) {
                __syncthreads();
                *(uint4*)&As[(srow)      * 32 + ch * 8] = a0;
                *(uint4*)&As[(srow + 64) * 32 + ch * 8] = a1;
                *(uint4*)&Bs[(srow)      * 32 + ch * 8] = b0;
                *(uint4*)&Bs[(srow + 64) * 32 + ch * 8] = b1;
                __syncthreads();
                short8 af[4], bfr[4];
#pragma unroll
                for (int i = 0; i < 4; ++i) af[i]  = *(const short8*)&As[(wm + i * 16 + lr) * 32 + quad * 8];
#pragma unroll
                for (int j = 0; j < 4; ++j) bfr[j] = *(const short8*)&Bs[(wn + j * 16 + lr) * 32 + quad * 8];
                if (k0 + 32 < 512) {
                    a0 = *(const uint4*)&A[(size_t)srow * 512 + k0 + 32 + ch * 8];
                    a1 = *(const uint4*)&A[(size_t)(srow + 64) * 512 + k0 + 32 + ch * 8];
                    b0 = *(const uint4*)&fcw_bf[(size_t)(n0 + srow)      * 512 + k0 + 32 + ch * 8];
                    b1 = *(const uint4*)&fcw_bf[(size_t)(n0 + srow + 64) * 512 + k0 + 32 + ch * 8];
                }
#pragma unroll
                for (int i = 0; i < 4; ++i)
#pragma unroll
                    for (int j = 0; j < 4; ++j) acc[i][j] = mfma16(af[i], bfr[j], acc[i][j]);
            }

#pragma unroll
            for (int i = 0; i < 4; ++i)
#pragma unroll
                for (int r = 0; r < 4; ++r) {
                    const int b = wm + i * 16 + quad * 4 + r;
                    const bool act = (t < len_i[b]);
                    const size_t base = (size_t)b * T_ * V_ + (size_t)t * V_;
#pragma unroll
                    for (int j = 0; j < 4; ++j) {
                        const int n = n0 + wn + j * 16 + lr;
                        if (n < V_) out[base + n] = act ? (acc[i][j][r] + fcb[j]) : 0.f;
                    }
                }
        }
    }
}

// ---------------------------------------------------------------------------
extern "C" void kernel_launch(void* const* d_in, const int* in_sizes, int n_in,
                              void* d_out, int out_size, void* d_ws, size_t ws_size,
                              hipStream_t stream) {
    const float* image_code = (const float*)d_in[0];
    const int*   captions   = (const int*)d_in[1];
    const int*   cap_lens   = (const int*)d_in[2];
    const float* embed_w    = (const float*)d_in[3];
    const float* W_ih       = (const float*)d_in[4];
    const float* W_hh       = (const float*)d_in[5];
    const float* b_ih       = (const float*)d_in[6];
    const float* b_hh       = (const float*)d_in[7];
    const float* fc_w       = (const float*)d_in[8];
    const float* fc_b       = (const float*)d_in[9];
    const float* init_w     = (const float*)d_in[10];
    const float* init_b     = (const float*)d_in[11];

    float* out = (float*)d_out;
    char* ws = (char*)d_ws;
    int*      order   = (int*)(ws + WS_ORDER);
    int*      len_i   = (int*)(ws + WS_LEN);
    int*      tok     = (int*)(ws + WS_TOK);
    int*      bar     = (int*)(ws + WS_BAR);
    float*    gi_img  = (float*)(ws + WS_GIIMG);
    ushort_t* whh_bf  = (ushort_t*)(ws + WS_WHH);
    ushort_t* gi_full = (ushort_t*)(ws + WS_GIFULL);
    ushort_t* outs_bf = (ushort_t*)(ws + WS_OUTS);
    ushort_t* fcw_bf  = (ushort_t*)(ws + WS_FCW);
    int*      sync    = (int*)(fcw_bf + ((size_t)NPAD_ - 4) * 512);

    // 1) one setup launch: prep + pfx (gi_img, h0) + both weight converts
    hipLaunchKernelGGL(k_setup, dim3(SU_N), dim3(256), 0, stream,
                       captions, cap_lens, fc_w, W_hh,
                       image_code, W_ih, b_ih, init_w, init_b,
                       fcw_bf, whh_bf, gi_img, outs_bf,
                       order, len_i, tok, bar,
                       out + (size_t)B_ * T_ * V_);

    // 2) gi_full = emb @ W_ih[:, 2048:]^T + gi_img[b] + b_hh(r,z)
    hipLaunchKernelGGL((gemm128<true, true, EpiAdd2D>), dim3(12, 31), dim3(256), 0, stream,
                       embed_w, WD_, tok, W_ih + IC_, D_, WD_,
                       EpiAdd2D{gi_full, G3_, gi_img, G3_, b_hh});

    // 3) fused persistent recurrence + streaming output projection (solo-CU)
    hipLaunchKernelGGL(k_fused, dim3(NPROD_ + NCONS_), dim3(256), 0, stream,
                       whh_bf, gi_full, b_hh, outs_bf,
                       fcw_bf, fc_b, len_i, out, sync);
}